// Round 15
// baseline (1201.365 us; speedup 1.0000x reference)
//
#include <hip/hip_runtime.h>
#include <hip/hip_bf16.h>
#include <cstdint>

// R14: attn = R13 + manual 2-deep software pipeline (K/V for step n+1 issued
// before step n's compute; static even/odd register buffers). Rest = R13.

typedef __bf16 bf16;
typedef __bf16 bf16x4 __attribute__((ext_vector_type(4)));
typedef __bf16 bf16x8 __attribute__((ext_vector_type(8)));
typedef float  f32x4  __attribute__((ext_vector_type(4)));

__device__ __forceinline__ void glds16(const void* g, void* l) {
  __builtin_amdgcn_global_load_lds(
      (const __attribute__((address_space(1))) void*)g,
      (__attribute__((address_space(3))) void*)l, 16, 0, 0);
}

#define MFMA(a, b, c) __builtin_amdgcn_mfma_f32_16x16x32_bf16((a), (b), (c), 0, 0, 0)

// ---------------- prep GEMM (m97-style 128x128, BK=32) ----------------
template<int EPI>
__global__ __launch_bounds__(256) void gemm_bt(
    const bf16* __restrict__ A, int lda, long long strideA,
    const bf16* __restrict__ W, long long strideW,
    const float* __restrict__ bias,
    void* __restrict__ Cv, int ldc, long long strideC, int K)
{
  __shared__ bf16 As[128 * 32];
  __shared__ bf16 Ws[128 * 32];
  const int tid = threadIdx.x;
  const int w = tid >> 6;
  const int l = tid & 63;

  const int nwg = gridDim.x * gridDim.y;
  const int orig = blockIdx.x + gridDim.x * blockIdx.y;
  const int q8 = nwg >> 3, r8 = nwg & 7;
  const int xcd = orig & 7, rem = orig >> 3;
  const int wgid = (xcd < r8 ? xcd * (q8 + 1) : r8 * (q8 + 1) + (xcd - r8) * q8) + rem;
  const int bx = wgid % gridDim.x;
  const int by = wgid / gridDim.x;

  const int z = blockIdx.z;
  A += (size_t)z * strideA;
  W += (size_t)z * strideW;

  const int rowBase = by * 128;
  const int colBase = bx * 128;
  const int wr = w >> 1, wc = w & 1;

  f32x4 acc[4][4] = {};

  const bf16* a0 = A + (size_t)(rowBase +      (tid >> 2)) * lda + (tid & 3) * 8;
  const bf16* a1 = A + (size_t)(rowBase + 64 + (tid >> 2)) * lda + (tid & 3) * 8;
  const bf16* w0 = W + (size_t)(colBase +      (tid >> 2)) * K   + (tid & 3) * 8;
  const bf16* w1 = W + (size_t)(colBase + 64 + (tid >> 2)) * K   + (tid & 3) * 8;
  bf16* lA0 = &As[w * 512];
  bf16* lA1 = &As[w * 512 + 2048];
  bf16* lW0 = &Ws[w * 512];
  bf16* lW1 = &Ws[w * 512 + 2048];

  const int arow = wr * 64 + (l & 15);
  const int brow = wc * 64 + (l & 15);
  const int koff = (l >> 4) * 8;

  for (int kt = 0; kt < K; kt += 32) {
    if (kt) __syncthreads();
    glds16(a0, lA0); glds16(a1, lA1);
    glds16(w0, lW0); glds16(w1, lW1);
    a0 += 32; a1 += 32; w0 += 32; w1 += 32;
    __syncthreads();
    bf16x8 af[4], bw[4];
#pragma unroll
    for (int m = 0; m < 4; ++m)
      af[m] = *(const bf16x8*)&As[(arow + m * 16) * 32 + koff];
#pragma unroll
    for (int n = 0; n < 4; ++n)
      bw[n] = *(const bf16x8*)&Ws[(brow + n * 16) * 32 + koff];
#pragma unroll
    for (int m = 0; m < 4; ++m)
#pragma unroll
      for (int n = 0; n < 4; ++n)
        acc[m][n] = MFMA(af[m], bw[n], acc[m][n]);
  }

#pragma unroll
  for (int m = 0; m < 4; ++m) {
#pragma unroll
    for (int n = 0; n < 4; ++n) {
      const int r0  = rowBase + wr * 64 + m * 16 + (l >> 4) * 4;
      const int col = colBase + wc * 64 + n * 16 + (l & 15);
      bf16* C = (bf16*)Cv + (size_t)z * strideC;
#pragma unroll
      for (int r = 0; r < 4; ++r)
        C[(size_t)(r0 + r) * ldc + col] = (bf16)acc[m][n][r];
    }
  }
}

// ---------------- in-loop GEMM: 64x128 tile, BK=64, swizzled LDS ----------------
template<int EPI, int SPLITK>
__global__ __launch_bounds__(256) void gemm_h64(
    const bf16* __restrict__ A, int lda,
    const bf16* __restrict__ W, int ldw,
    const float* __restrict__ bias,
    void* __restrict__ Cv, int ldc, int K,
    bf16* __restrict__ Vtp, bf16* __restrict__ Vts, bf16* __restrict__ Vtt)
{
  __shared__ bf16 As[64 * 64];
  __shared__ bf16 Ws[128 * 64];
  const int tid = threadIdx.x;
  const int w = tid >> 6, l = tid & 63;

  const int nwg = gridDim.x * gridDim.y;
  const int orig = blockIdx.x + gridDim.x * blockIdx.y;
  const int q8 = nwg >> 3, r8 = nwg & 7;
  const int xcd = orig & 7, rem = orig >> 3;
  const int wgid = (xcd < r8 ? xcd * (q8 + 1) : r8 * (q8 + 1) + (xcd - r8) * q8) + rem;
  const int bx = wgid % gridDim.x;
  const int by = wgid / gridDim.x;

  const int rowBase = by * 64, colBase = bx * 128;
  const int Kper = K / SPLITK;
  const int kz = blockIdx.z;

  f32x4 acc[4][2] = {};

  const bf16* aSrc[2];
  const bf16* wSrc[4];
#pragma unroll
  for (int i = 0; i < 2; ++i) {
    int ci = i * 256 + tid, row = ci >> 3, k8 = ci & 7;
    aSrc[i] = A + (size_t)(rowBase + row) * lda + kz * Kper + ((k8 ^ (row & 7)) << 3);
  }
#pragma unroll
  for (int i = 0; i < 4; ++i) {
    int ci = i * 256 + tid, row = ci >> 3, k8 = ci & 7;
    wSrc[i] = W + (size_t)(colBase + row) * ldw + kz * Kper + ((k8 ^ (row & 7)) << 3);
  }
  bf16* aDst[2] = { &As[w * 512], &As[2048 + w * 512] };
  bf16* wDst[4] = { &Ws[w * 512], &Ws[2048 + w * 512],
                    &Ws[4096 + w * 512], &Ws[6144 + w * 512] };

  const int c15 = l & 15, g = l >> 4;

  for (int kt = 0; kt < Kper; kt += 64) {
    if (kt) __syncthreads();
    glds16(aSrc[0], aDst[0]); glds16(aSrc[1], aDst[1]);
#pragma unroll
    for (int i = 0; i < 4; ++i) glds16(wSrc[i], wDst[i]);
    aSrc[0] += 64; aSrc[1] += 64;
#pragma unroll
    for (int i = 0; i < 4; ++i) wSrc[i] += 64;
    __syncthreads();
#pragma unroll
    for (int kh = 0; kh < 2; ++kh) {
      const int ks = g + 4 * kh;
      bf16x8 af[4], bw[2];
#pragma unroll
      for (int m = 0; m < 4; ++m) {
        const int row = c15 + m * 16;
        af[m] = *(const bf16x8*)&As[row * 64 + ((ks ^ (row & 7)) << 3)];
      }
#pragma unroll
      for (int n = 0; n < 2; ++n) {
        const int row = w * 32 + n * 16 + c15;
        bw[n] = *(const bf16x8*)&Ws[row * 64 + ((ks ^ (row & 7)) << 3)];
      }
#pragma unroll
      for (int m = 0; m < 4; ++m)
#pragma unroll
        for (int n = 0; n < 2; ++n)
          acc[m][n] = MFMA(af[m], bw[n], acc[m][n]);
    }
  }

#pragma unroll
  for (int m = 0; m < 4; ++m) {
#pragma unroll
    for (int n = 0; n < 2; ++n) {
      const int r0  = rowBase + m * 16 + g * 4;
      const int col = colBase + w * 32 + n * 16 + c15;
      const float bv = bias[col];
      if (EPI == 2) {
        float* C = (float*)Cv;
        const float badd = (SPLITK == 1 || kz == 0) ? bv : 0.f;
#pragma unroll
        for (int r = 0; r < 4; ++r)
          atomicAdd(&C[(size_t)(r0 + r) * ldc + col], acc[m][n][r] + badd);
      } else if (EPI == 3) {
        bf16* vdst = nullptr;
        if (col >= 512 && col < 768)        vdst = Vtp + (size_t)(col - 512)  * 4096;
        else if (col >= 1280 && col < 1536) vdst = Vts + (size_t)(col - 1280) * 4096;
        else if (col >= 1792)               vdst = Vtt + (size_t)(col - 1792) * 4096;
        if (vdst) {
          bf16x4 o4;
#pragma unroll
          for (int r = 0; r < 4; ++r) o4[r] = (bf16)(acc[m][n][r] + bv);
          *(bf16x4*)(vdst + r0) = o4;
        } else {
          bf16* C = (bf16*)Cv;
#pragma unroll
          for (int r = 0; r < 4; ++r)
            C[(size_t)(r0 + r) * ldc + col] = (bf16)(acc[m][n][r] + bv);
        }
      } else {
        bf16* C = (bf16*)Cv;
#pragma unroll
        for (int r = 0; r < 4; ++r) {
          float v = acc[m][n][r] + bv;
          if (EPI == 1) v = fmaxf(v, 0.f);
          C[(size_t)(r0 + r) * ldc + col] = (bf16)v;
        }
      }
    }
  }
}

// ---------------- attention: swapped-QK, no-max exp, pipelined, 1 wave/block ----------------
// 2560 x 64-thread blocks. 2-deep K/V register pipeline: loads for step n+1
// issued before step n's compute. Static even/odd buffers (no runtime indexing).
__global__ __launch_bounds__(64) void attn_full(
    const bf16* __restrict__ qkv,
    const bf16* __restrict__ Vtp, const bf16* __restrict__ Vts,
    const bf16* __restrict__ Vtt,
    const bf16* __restrict__ pmb, bf16* __restrict__ out)
{
  __shared__ __align__(16) bf16 P_lds[2][16][40];
  const int orig = blockIdx.x;                 // 2560 = 8 XCD * 320
  const int id = (orig & 7) * 320 + (orig >> 3);
  const bf16* Vt; int qoff, koff, colOff; bool bias;
  int b, h, qb;
  if (id < 1024) {
    Vt = Vtp; qoff = 0; koff = 256; colOff = 0; bias = false;
    b = id >> 7; h = (id >> 5) & 3; qb = id & 31;
  } else if (id < 2048) {
    int i = id - 1024;
    Vt = Vts; qoff = 768; koff = 1024; colOff = 256; bias = true;
    b = i >> 7; h = (i >> 5) & 3; qb = i & 31;
  } else {
    int i = id - 2048;
    Vt = Vtt; qoff = 1536; koff = 1664; colOff = 512; bias = false;
    b = i >> 6; h = (i >> 5) & 1; qb = i & 31;
  }
  const int E3 = 1920;
  const int qcol = h * 64;
  const int l = threadIdx.x;
  const int g = l >> 4, c = l & 15;
  const int q0 = qb * 16;
  const int tok0 = b * 512;
  const float scale = 0.125f;

  const bf16* qrow = qkv + (size_t)(tok0 + q0 + c) * E3 + qoff + qcol;
  bf16x8 qf0 = *(const bf16x8*)(qrow + g * 8);
  bf16x8 qf1 = *(const bf16x8*)(qrow + 32 + g * 8);
  const bf16* Kb = qkv + (size_t)tok0 * E3 + koff + qcol;
  const bf16* pmq = pmb + (size_t)(tok0 + q0 + c) * 512;   // q = c (swapped layout)

  float sm = 0.f;
  f32x4 oT[4] = {};

  auto LK = [&](int kt, bf16x8 (&ka)[4], bf16x8 (&kb)[4]) {
#pragma unroll
    for (int j = 0; j < 4; ++j) {
      const bf16* kp = Kb + (size_t)(kt + 16 * j + c) * E3 + g * 8;
      ka[j] = *(const bf16x8*)kp;
      kb[j] = *(const bf16x8*)(kp + 32);
    }
  };
  auto LV = [&](int kt, bf16x8 (&vf)[2][4]) {
#pragma unroll
    for (int hf = 0; hf < 2; ++hf)
#pragma unroll
      for (int dt = 0; dt < 4; ++dt)
        vf[hf][dt] = *(const bf16x8*)(Vt + (size_t)(qcol + dt * 16 + c) * 4096
                                      + tok0 + kt + hf * 32 + g * 8);
  };
  auto STEP = [&](int kt, bf16x8 (&ka)[4], bf16x8 (&kb)[4], bf16x8 (&vf)[2][4]) {
    f32x4 s[4] = {};
    __builtin_amdgcn_s_setprio(1);
#pragma unroll
    for (int j = 0; j < 4; ++j) {
      s[j] = MFMA(ka[j], qf0, s[j]);
      s[j] = MFMA(kb[j], qf1, s[j]);
    }
    __builtin_amdgcn_s_setprio(0);
#pragma unroll
    for (int j = 0; j < 4; ++j) {
      bf16x4 e;
      float a0 = s[j][0] * scale, a1 = s[j][1] * scale;
      float a2 = s[j][2] * scale, a3 = s[j][3] * scale;
      if (bias) {
        bf16x4 bb = *(const bf16x4*)(pmq + kt + 16 * j + 4 * g);
        a0 += (float)bb[0]; a1 += (float)bb[1];
        a2 += (float)bb[2]; a3 += (float)bb[3];
      }
      float x0 = __expf(a0), x1 = __expf(a1);
      float x2 = __expf(a2), x3 = __expf(a3);
      sm += (x0 + x1) + (x2 + x3);
      e[0] = (bf16)x0; e[1] = (bf16)x1; e[2] = (bf16)x2; e[3] = (bf16)x3;
      *(bf16x4*)&P_lds[j >> 1][c][(j & 1) * 16 + 4 * g] = e;
    }
    asm volatile("s_waitcnt lgkmcnt(0)" ::: "memory");
    __builtin_amdgcn_s_setprio(1);
#pragma unroll
    for (int hf = 0; hf < 2; ++hf) {
      bf16x8 pf = *(const bf16x8*)&P_lds[hf][c][g * 8];
#pragma unroll
      for (int dt = 0; dt < 4; ++dt)
        oT[dt] = MFMA(vf[hf][dt], pf, oT[dt]);
    }
    __builtin_amdgcn_s_setprio(0);
  };

  bf16x8 kEvA[4], kEvB[4], kOdA[4], kOdB[4];
  bf16x8 vEv[2][4], vOd[2][4];
  LK(0, kEvA, kEvB);
  LV(0, vEv);
#pragma unroll
  for (int it = 0; it < 4; ++it) {
    const int kt = it * 128;
    LK(kt + 64, kOdA, kOdB);      // prefetch odd step
    LV(kt + 64, vOd);
    STEP(kt, kEvA, kEvB, vEv);    // compute even step (loads in flight)
    if (it < 3) {
      LK(kt + 128, kEvA, kEvB);   // prefetch next even step
      LV(kt + 128, vEv);
    }
    STEP(kt + 64, kOdA, kOdB, vOd);
  }

  // full row-sum for q=c: reduce over the 4 lanes sharing c
  sm += __shfl_xor(sm, 16);
  sm += __shfl_xor(sm, 32);
  const float inv = 1.0f / sm;
#pragma unroll
  for (int dt = 0; dt < 4; ++dt) {
    bf16x4 o4;
#pragma unroll
    for (int r = 0; r < 4; ++r) o4[r] = (bf16)(oT[dt][r] * inv);
    *(bf16x4*)(out + (size_t)(tok0 + q0 + c) * 640 + colOff + qcol + dt * 16 + 4 * g) = o4;
  }
}

// LayerNorm over D=640, one wave per row, bf16 out.
__global__ __launch_bounds__(256) void ln_kernel(
    const float* __restrict__ x, const float* __restrict__ sca,
    const float* __restrict__ bia, bf16* __restrict__ out)
{
  const int w = threadIdx.x >> 6, l = threadIdx.x & 63;
  const int row = blockIdx.x * 4 + w;
  const float* xr = x + (size_t)row * 640;
  float v[10], sum = 0.f, sq = 0.f;
#pragma unroll
  for (int i = 0; i < 10; ++i) {
    v[i] = xr[l + 64 * i];
    sum += v[i]; sq += v[i] * v[i];
  }
#pragma unroll
  for (int m = 1; m <= 32; m <<= 1) {
    sum += __shfl_xor(sum, m);
    sq  += __shfl_xor(sq, m);
  }
  const float mean = sum * (1.f / 640.f);
  const float var  = sq * (1.f / 640.f) - mean * mean;
  const float rstd = rsqrtf(var + 1e-5f);
  bf16* orow = out + (size_t)row * 640;
#pragma unroll
  for (int i = 0; i < 10; ++i) {
    const int c = l + 64 * i;
    orow[c] = (bf16)((v[i] - mean) * rstd * sca[c] + bia[c]);
  }
}

__global__ void cvt_bf16_k(const float* __restrict__ src, bf16* __restrict__ dst,
                           int perL, int dstStride, int dstOff, int total, float scl)
{
  int i = blockIdx.x * 256 + threadIdx.x;
  if (i >= total) return;
  int l = i / perL, j = i - l * perL;
  dst[(size_t)l * dstStride + dstOff + j] = (bf16)(scl * src[i]);
}

__global__ void cvt_f32_k(const float* __restrict__ src, float* __restrict__ dst,
                          int perL, int dstStride, int dstOff, int total)
{
  int i = blockIdx.x * 256 + threadIdx.x;
  if (i >= total) return;
  int l = i / perL, j = i - l * perL;
  dst[(size_t)l * dstStride + dstOff + j] = src[i];
}

__global__ void tcvt_k(const float* __restrict__ src, bf16* __restrict__ dst,
                       int R, int C)
{
  __shared__ float t[32][33];
  const int lz = blockIdx.z;
  src += (size_t)lz * R * C;
  dst += (size_t)lz * R * C;
  const int c0 = blockIdx.x * 32, r0 = blockIdx.y * 32;
  const int tx = threadIdx.x & 31, ty = threadIdx.x >> 5;
#pragma unroll
  for (int i = ty; i < 32; i += 8)
    t[i][tx] = src[(size_t)(r0 + i) * C + c0 + tx];
  __syncthreads();
#pragma unroll
  for (int i = ty; i < 32; i += 8)
    dst[(size_t)(c0 + i) * R + r0 + tx] = (bf16)t[tx][i];
}

__global__ void biasmix_k(const float* __restrict__ b2, int b2S,
                          const float* __restrict__ W2, long long w2S, int ldw,
                          const float* __restrict__ b1, int b1S,
                          float* __restrict__ dst, int dstS, int dstOff,
                          int M, int K)
{
  const int lz = blockIdx.y;
  const int w = threadIdx.x >> 6, lane = threadIdx.x & 63;
  const int m = blockIdx.x * 4 + w;
  if (m >= M) return;
  const float* wr = W2 + (size_t)lz * w2S + (size_t)m * ldw;
  const float* br = b1 + (size_t)lz * b1S;
  float s = 0.f;
  for (int k = lane; k < K; k += 64) s += wr[k] * br[k];
#pragma unroll
  for (int msk = 1; msk <= 32; msk <<= 1) s += __shfl_xor(s, msk);
  if (lane == 0)
    dst[(size_t)lz * dstS + dstOff + m] = s + b2[(size_t)lz * b2S + m];
}

__global__ void copy_f32(const float* __restrict__ src, float* __restrict__ dst, int n)
{
  int i = blockIdx.x * 256 + threadIdx.x;
  if (i < n) dst[i] = src[i];
}

extern "C" void kernel_launch(void* const* d_in, const int* in_sizes, int n_in,
                              void* d_out, int out_size, void* d_ws, size_t ws_size,
                              hipStream_t stream)
{
  (void)in_sizes; (void)n_in; (void)ws_size;
  const float* src    = (const float*)d_in[0];
  const float* pmask  = (const float*)d_in[1];
  const float* n1_s   = (const float*)d_in[3];
  const float* n1_b   = (const float*)d_in[4];
  const float* pin_W  = (const float*)d_in[5];
  const float* pin_b  = (const float*)d_in[6];
  const float* sin_W  = (const float*)d_in[7];
  const float* sin_b  = (const float*)d_in[8];
  const float* tin_W  = (const float*)d_in[9];
  const float* tin_b  = (const float*)d_in[10];
  const float* pqkv_W = (const float*)d_in[11];
  const float* pqkv_b = (const float*)d_in[12];
  const float* pout_W = (const float*)d_in[13];
  const float* pout_b = (const float*)d_in[14];
  const float* sqkv_W = (const float*)d_in[15];
  const float* sqkv_b = (const float*)d_in[16];
  const float* sout_W = (const float*)d_in[17];
  const float* sout_b = (const float*)d_in[18];
  const float* tqkv_W = (const float*)d_in[19];
  const float* tqkv_b = (const float*)d_in[20];
  const float* tout_W = (const float*)d_in[21];
  const float* tout_b = (const float*)d_in[22];
  const float* o_W    = (const float*)d_in[23];
  const float* o_b    = (const float*)d_in[24];
  const float* ff1_W  = (const float*)d_in[25];
  const float* ff1_b  = (const float*)d_in[26];
  const float* ff2_W  = (const float*)d_in[27];
  const float* ff2_b  = (const float*)d_in[28];
  const float* n2_s   = (const float*)d_in[29];
  const float* n2_b   = (const float*)d_in[30];

  char* wsp = (char*)d_ws;
  auto alloc = [&](size_t bytes) {
    char* p = wsp;
    wsp += (bytes + 255) & ~(size_t)255;
    return p;
  };
  bf16*  Wbig   = (bf16*)alloc(6ull * 1920 * 640 * 2);
  float* bbig   = (float*)alloc(6ull * 1920 * 4);
  bf16*  Weff   = (bf16*)alloc(6ull * 640 * 640 * 2);
  float* beff   = (float*)alloc(6ull * 640 * 4);
  float* catb   = (float*)alloc(6ull * 640 * 4);
  bf16*  Wf1    = (bf16*)alloc(6ull * 2048 * 640 * 2);
  bf16*  Wf2    = (bf16*)alloc(6ull * 2048 * 640 * 2);
  bf16*  xn     = (bf16*)alloc(4096ull * 640 * 2);
  bf16*  Vtp    = (bf16*)alloc(256ull * 4096 * 2);
  bf16*  Vts    = (bf16*)alloc(256ull * 4096 * 2);
  bf16*  Vtt    = (bf16*)alloc(128ull * 4096 * 2);
  bf16*  ao     = (bf16*)alloc(4096ull * 640 * 2);
  bf16*  pmb    = (bf16*)alloc(8ull * 512 * 512 * 2);
  char*  region = alloc(4096ull * 1920 * 2 + 4096ull * 2048 * 2);
  bf16*  qkv    = (bf16*)region;
  bf16*  hbuf   = (bf16*)(region + 4096ull * 1920 * 2);
  char* pr = region;
  auto palloc = [&](size_t bytes) {
    char* p = pr;
    pr += (bytes + 255) & ~(size_t)255;
    return p;
  };
  bf16* Wpq  = (bf16*)palloc(6ull * 768 * 256 * 2);
  bf16* Wsq  = (bf16*)palloc(6ull * 768 * 256 * 2);
  bf16* Wtq  = (bf16*)palloc(6ull * 384 * 128 * 2);
  bf16* pinT = (bf16*)palloc(6ull * 640 * 256 * 2);
  bf16* sinT = (bf16*)palloc(6ull * 640 * 256 * 2);
  bf16* tinT = (bf16*)palloc(6ull * 640 * 128 * 2);
  bf16* Wobf = (bf16*)palloc(6ull * 640 * 640 * 2);
  bf16* WpoT = (bf16*)palloc(6ull * 256 * 256 * 2);
  bf16* WsoT = (bf16*)palloc(6ull * 256 * 256 * 2);
  bf16* WtoT = (bf16*)palloc(6ull * 128 * 128 * 2);

  float* x = (float*)d_out;

  auto cvt = [&](const float* s, bf16* d, int perL) {
    int total = 6 * perL;
    cvt_bf16_k<<<(total + 255) / 256, 256, 0, stream>>>(s, d, perL, perL, 0, total, 1.f);
  };
  cvt(pqkv_W, Wpq, 768 * 256);
  cvt(sqkv_W, Wsq, 768 * 256);
  cvt(tqkv_W, Wtq, 384 * 128);
  cvt(o_W,    Wobf, 640 * 640);
  cvt(ff1_W,  Wf1, 2048 * 640);
  cvt(ff2_W,  Wf2, 2048 * 640);
  {
    int total = 8 * 512 * 512;
    cvt_bf16_k<<<(total + 255) / 256, 256, 0, stream>>>(pmask, pmb, total, total, 0, total, 2.f);
  }
  tcvt_k<<<dim3(20, 8, 6), 256, 0, stream>>>(pin_W, pinT, 256, 640);
  tcvt_k<<<dim3(20, 8, 6), 256, 0, stream>>>(sin_W, sinT, 256, 640);
  tcvt_k<<<dim3(20, 4, 6), 256, 0, stream>>>(tin_W, tinT, 128, 640);
  tcvt_k<<<dim3(8, 8, 6), 256, 0, stream>>>(pout_W, WpoT, 256, 256);
  tcvt_k<<<dim3(8, 8, 6), 256, 0, stream>>>(sout_W, WsoT, 256, 256);
  tcvt_k<<<dim3(4, 4, 6), 256, 0, stream>>>(tout_W, WtoT, 128, 128);
  biasmix_k<<<dim3(192, 6), 256, 0, stream>>>(pqkv_b, 768, pqkv_W, 768 * 256, 256,
                                              pin_b, 256, bbig, 1920, 0, 768, 256);
  biasmix_k<<<dim3(192, 6), 256, 0, stream>>>(sqkv_b, 768, sqkv_W, 768 * 256, 256,
                                              sin_b, 256, bbig, 1920, 768, 768, 256);
  biasmix_k<<<dim3(96, 6), 256, 0, stream>>>(tqkv_b, 384, tqkv_W, 384 * 128, 128,
                                             tin_b, 128, bbig, 1920, 1536, 384, 128);
  cvt_f32_k<<<dim3(6), 256, 0, stream>>>(pout_b, catb, 256, 640, 0,   6 * 256);
  cvt_f32_k<<<dim3(6), 256, 0, stream>>>(sout_b, catb, 256, 640, 256, 6 * 256);
  cvt_f32_k<<<dim3(3), 256, 0, stream>>>(tout_b, catb, 128, 640, 512, 6 * 128);
  biasmix_k<<<dim3(160, 6), 256, 0, stream>>>(o_b, 640, o_W, 640 * 640, 640,
                                              catb, 640, beff, 640, 0, 640, 640);
  gemm_bt<0><<<dim3(5, 6, 6), 256, 0, stream>>>(Wpq, 256, 768 * 256, pinT, 640 * 256,
      nullptr, Wbig, 640, 1920 * 640, 256);
  gemm_bt<0><<<dim3(5, 6, 6), 256, 0, stream>>>(Wsq, 256, 768 * 256, sinT, 640 * 256,
      nullptr, Wbig + 768 * 640, 640, 1920 * 640, 256);
  gemm_bt<0><<<dim3(5, 3, 6), 256, 0, stream>>>(Wtq, 128, 384 * 128, tinT, 640 * 128,
      nullptr, Wbig + 1536 * 640, 640, 1920 * 640, 128);
  gemm_bt<0><<<dim3(2, 5, 6), 256, 0, stream>>>(Wobf, 640, 640 * 640, WpoT, 256 * 256,
      nullptr, Weff, 640, 640 * 640, 256);
  gemm_bt<0><<<dim3(2, 5, 6), 256, 0, stream>>>(Wobf + 256, 640, 640 * 640, WsoT, 256 * 256,
      nullptr, Weff + 256, 640, 640 * 640, 256);
  gemm_bt<0><<<dim3(1, 5, 6), 256, 0, stream>>>(Wobf + 512, 640, 640 * 640, WtoT, 128 * 128,
      nullptr, Weff + 512, 640, 640 * 640, 128);

  copy_f32<<<(out_size + 255) / 256, 256, 0, stream>>>(src, x, out_size);

  for (int l = 0; l < 6; ++l) {
    ln_kernel<<<1024, 256, 0, stream>>>(x, n1_s + l * 640, n1_b + l * 640, xn);
    gemm_h64<3, 1><<<dim3(15, 64), 256, 0, stream>>>(xn, 640,
        Wbig + (size_t)l * 1920 * 640, 640, bbig + l * 1920,
        qkv, 1920, 640, Vtp, Vts, Vtt);
    attn_full<<<2560, 64, 0, stream>>>(qkv, Vtp, Vts, Vtt, pmb, ao);
    gemm_h64<2, 2><<<dim3(5, 64, 2), 256, 0, stream>>>(ao, 640,
        Weff + (size_t)l * 640 * 640, 640, beff + l * 640,
        x, 640, 640, nullptr, nullptr, nullptr);
    ln_kernel<<<1024, 256, 0, stream>>>(x, n2_s + l * 640, n2_b + l * 640, xn);
    gemm_h64<1, 1><<<dim3(16, 64), 256, 0, stream>>>(xn, 640,
        Wf1 + (size_t)l * 2048 * 640, 640, ff1_b + l * 2048,
        hbuf, 2048, 640, nullptr, nullptr, nullptr);
    gemm_h64<2, 4><<<dim3(5, 64, 4), 256, 0, stream>>>(hbuf, 2048,
        Wf2 + (size_t)l * 2048 * 640, 2048, ff2_b + l * 640,
        x, 640, 2048, nullptr, nullptr, nullptr);
  }
}

// Round 16
// 1083.492 us; speedup vs baseline: 1.1088x; 1.1088x over previous
//
#include <hip/hip_runtime.h>
#include <hip/hip_bf16.h>
#include <cstdint>

// R15: consolidation - exact R13 (measured best, 1086us).
// attn: swapped-QK, no-max exp, KVBLK=64, 1-wave blocks (2560x64), setprio.
// GEMM: gemm_h64 64x128/BK=64 swizzled + split-K atomics; fused qkv/out weights.

typedef __bf16 bf16;
typedef __bf16 bf16x4 __attribute__((ext_vector_type(4)));
typedef __bf16 bf16x8 __attribute__((ext_vector_type(8)));
typedef float  f32x4  __attribute__((ext_vector_type(4)));

__device__ __forceinline__ void glds16(const void* g, void* l) {
  __builtin_amdgcn_global_load_lds(
      (const __attribute__((address_space(1))) void*)g,
      (__attribute__((address_space(3))) void*)l, 16, 0, 0);
}

#define MFMA(a, b, c) __builtin_amdgcn_mfma_f32_16x16x32_bf16((a), (b), (c), 0, 0, 0)

// ---------------- prep GEMM (m97-style 128x128, BK=32) ----------------
template<int EPI>
__global__ __launch_bounds__(256) void gemm_bt(
    const bf16* __restrict__ A, int lda, long long strideA,
    const bf16* __restrict__ W, long long strideW,
    const float* __restrict__ bias,
    void* __restrict__ Cv, int ldc, long long strideC, int K)
{
  __shared__ bf16 As[128 * 32];
  __shared__ bf16 Ws[128 * 32];
  const int tid = threadIdx.x;
  const int w = tid >> 6;
  const int l = tid & 63;

  const int nwg = gridDim.x * gridDim.y;
  const int orig = blockIdx.x + gridDim.x * blockIdx.y;
  const int q8 = nwg >> 3, r8 = nwg & 7;
  const int xcd = orig & 7, rem = orig >> 3;
  const int wgid = (xcd < r8 ? xcd * (q8 + 1) : r8 * (q8 + 1) + (xcd - r8) * q8) + rem;
  const int bx = wgid % gridDim.x;
  const int by = wgid / gridDim.x;

  const int z = blockIdx.z;
  A += (size_t)z * strideA;
  W += (size_t)z * strideW;

  const int rowBase = by * 128;
  const int colBase = bx * 128;
  const int wr = w >> 1, wc = w & 1;

  f32x4 acc[4][4] = {};

  const bf16* a0 = A + (size_t)(rowBase +      (tid >> 2)) * lda + (tid & 3) * 8;
  const bf16* a1 = A + (size_t)(rowBase + 64 + (tid >> 2)) * lda + (tid & 3) * 8;
  const bf16* w0 = W + (size_t)(colBase +      (tid >> 2)) * K   + (tid & 3) * 8;
  const bf16* w1 = W + (size_t)(colBase + 64 + (tid >> 2)) * K   + (tid & 3) * 8;
  bf16* lA0 = &As[w * 512];
  bf16* lA1 = &As[w * 512 + 2048];
  bf16* lW0 = &Ws[w * 512];
  bf16* lW1 = &Ws[w * 512 + 2048];

  const int arow = wr * 64 + (l & 15);
  const int brow = wc * 64 + (l & 15);
  const int koff = (l >> 4) * 8;

  for (int kt = 0; kt < K; kt += 32) {
    if (kt) __syncthreads();
    glds16(a0, lA0); glds16(a1, lA1);
    glds16(w0, lW0); glds16(w1, lW1);
    a0 += 32; a1 += 32; w0 += 32; w1 += 32;
    __syncthreads();
    bf16x8 af[4], bw[4];
#pragma unroll
    for (int m = 0; m < 4; ++m)
      af[m] = *(const bf16x8*)&As[(arow + m * 16) * 32 + koff];
#pragma unroll
    for (int n = 0; n < 4; ++n)
      bw[n] = *(const bf16x8*)&Ws[(brow + n * 16) * 32 + koff];
#pragma unroll
    for (int m = 0; m < 4; ++m)
#pragma unroll
      for (int n = 0; n < 4; ++n)
        acc[m][n] = MFMA(af[m], bw[n], acc[m][n]);
  }

#pragma unroll
  for (int m = 0; m < 4; ++m) {
#pragma unroll
    for (int n = 0; n < 4; ++n) {
      const int r0  = rowBase + wr * 64 + m * 16 + (l >> 4) * 4;
      const int col = colBase + wc * 64 + n * 16 + (l & 15);
      bf16* C = (bf16*)Cv + (size_t)z * strideC;
#pragma unroll
      for (int r = 0; r < 4; ++r)
        C[(size_t)(r0 + r) * ldc + col] = (bf16)acc[m][n][r];
    }
  }
}

// ---------------- in-loop GEMM: 64x128 tile, BK=64, swizzled LDS ----------------
template<int EPI, int SPLITK>
__global__ __launch_bounds__(256) void gemm_h64(
    const bf16* __restrict__ A, int lda,
    const bf16* __restrict__ W, int ldw,
    const float* __restrict__ bias,
    void* __restrict__ Cv, int ldc, int K,
    bf16* __restrict__ Vtp, bf16* __restrict__ Vts, bf16* __restrict__ Vtt)
{
  __shared__ bf16 As[64 * 64];
  __shared__ bf16 Ws[128 * 64];
  const int tid = threadIdx.x;
  const int w = tid >> 6, l = tid & 63;

  const int nwg = gridDim.x * gridDim.y;
  const int orig = blockIdx.x + gridDim.x * blockIdx.y;
  const int q8 = nwg >> 3, r8 = nwg & 7;
  const int xcd = orig & 7, rem = orig >> 3;
  const int wgid = (xcd < r8 ? xcd * (q8 + 1) : r8 * (q8 + 1) + (xcd - r8) * q8) + rem;
  const int bx = wgid % gridDim.x;
  const int by = wgid / gridDim.x;

  const int rowBase = by * 64, colBase = bx * 128;
  const int Kper = K / SPLITK;
  const int kz = blockIdx.z;

  f32x4 acc[4][2] = {};

  const bf16* aSrc[2];
  const bf16* wSrc[4];
#pragma unroll
  for (int i = 0; i < 2; ++i) {
    int ci = i * 256 + tid, row = ci >> 3, k8 = ci & 7;
    aSrc[i] = A + (size_t)(rowBase + row) * lda + kz * Kper + ((k8 ^ (row & 7)) << 3);
  }
#pragma unroll
  for (int i = 0; i < 4; ++i) {
    int ci = i * 256 + tid, row = ci >> 3, k8 = ci & 7;
    wSrc[i] = W + (size_t)(colBase + row) * ldw + kz * Kper + ((k8 ^ (row & 7)) << 3);
  }
  bf16* aDst[2] = { &As[w * 512], &As[2048 + w * 512] };
  bf16* wDst[4] = { &Ws[w * 512], &Ws[2048 + w * 512],
                    &Ws[4096 + w * 512], &Ws[6144 + w * 512] };

  const int c15 = l & 15, g = l >> 4;

  for (int kt = 0; kt < Kper; kt += 64) {
    if (kt) __syncthreads();
    glds16(aSrc[0], aDst[0]); glds16(aSrc[1], aDst[1]);
#pragma unroll
    for (int i = 0; i < 4; ++i) glds16(wSrc[i], wDst[i]);
    aSrc[0] += 64; aSrc[1] += 64;
#pragma unroll
    for (int i = 0; i < 4; ++i) wSrc[i] += 64;
    __syncthreads();
#pragma unroll
    for (int kh = 0; kh < 2; ++kh) {
      const int ks = g + 4 * kh;
      bf16x8 af[4], bw[2];
#pragma unroll
      for (int m = 0; m < 4; ++m) {
        const int row = c15 + m * 16;
        af[m] = *(const bf16x8*)&As[row * 64 + ((ks ^ (row & 7)) << 3)];
      }
#pragma unroll
      for (int n = 0; n < 2; ++n) {
        const int row = w * 32 + n * 16 + c15;
        bw[n] = *(const bf16x8*)&Ws[row * 64 + ((ks ^ (row & 7)) << 3)];
      }
#pragma unroll
      for (int m = 0; m < 4; ++m)
#pragma unroll
        for (int n = 0; n < 2; ++n)
          acc[m][n] = MFMA(af[m], bw[n], acc[m][n]);
    }
  }

#pragma unroll
  for (int m = 0; m < 4; ++m) {
#pragma unroll
    for (int n = 0; n < 2; ++n) {
      const int r0  = rowBase + m * 16 + g * 4;
      const int col = colBase + w * 32 + n * 16 + c15;
      const float bv = bias[col];
      if (EPI == 2) {
        float* C = (float*)Cv;
        const float badd = (SPLITK == 1 || kz == 0) ? bv : 0.f;
#pragma unroll
        for (int r = 0; r < 4; ++r)
          atomicAdd(&C[(size_t)(r0 + r) * ldc + col], acc[m][n][r] + badd);
      } else if (EPI == 3) {
        bf16* vdst = nullptr;
        if (col >= 512 && col < 768)        vdst = Vtp + (size_t)(col - 512)  * 4096;
        else if (col >= 1280 && col < 1536) vdst = Vts + (size_t)(col - 1280) * 4096;
        else if (col >= 1792)               vdst = Vtt + (size_t)(col - 1792) * 4096;
        if (vdst) {
          bf16x4 o4;
#pragma unroll
          for (int r = 0; r < 4; ++r) o4[r] = (bf16)(acc[m][n][r] + bv);
          *(bf16x4*)(vdst + r0) = o4;
        } else {
          bf16* C = (bf16*)Cv;
#pragma unroll
          for (int r = 0; r < 4; ++r)
            C[(size_t)(r0 + r) * ldc + col] = (bf16)(acc[m][n][r] + bv);
        }
      } else {
        bf16* C = (bf16*)Cv;
#pragma unroll
        for (int r = 0; r < 4; ++r) {
          float v = acc[m][n][r] + bv;
          if (EPI == 1) v = fmaxf(v, 0.f);
          C[(size_t)(r0 + r) * ldc + col] = (bf16)v;
        }
      }
    }
  }
}

// ---------------- attention: swapped-QK, no-max exp, KVBLK=64, 1 wave/block ----------------
__global__ __launch_bounds__(64) void attn_full(
    const bf16* __restrict__ qkv,
    const bf16* __restrict__ Vtp, const bf16* __restrict__ Vts,
    const bf16* __restrict__ Vtt,
    const bf16* __restrict__ pmb, bf16* __restrict__ out)
{
  __shared__ __align__(16) bf16 P_lds[2][16][40];
  const int orig = blockIdx.x;                 // 2560 = 8 XCD * 320
  const int id = (orig & 7) * 320 + (orig >> 3);
  const bf16* Vt; int qoff, koff, colOff; bool bias;
  int b, h, qb;
  if (id < 1024) {
    Vt = Vtp; qoff = 0; koff = 256; colOff = 0; bias = false;
    b = id >> 7; h = (id >> 5) & 3; qb = id & 31;
  } else if (id < 2048) {
    int i = id - 1024;
    Vt = Vts; qoff = 768; koff = 1024; colOff = 256; bias = true;
    b = i >> 7; h = (i >> 5) & 3; qb = i & 31;
  } else {
    int i = id - 2048;
    Vt = Vtt; qoff = 1536; koff = 1664; colOff = 512; bias = false;
    b = i >> 6; h = (i >> 5) & 1; qb = i & 31;
  }
  const int E3 = 1920;
  const int qcol = h * 64;
  const int l = threadIdx.x;
  const int g = l >> 4, c = l & 15;
  const int q0 = qb * 16;
  const int tok0 = b * 512;
  const float scale = 0.125f;

  const bf16* qrow = qkv + (size_t)(tok0 + q0 + c) * E3 + qoff + qcol;
  bf16x8 qf0 = *(const bf16x8*)(qrow + g * 8);
  bf16x8 qf1 = *(const bf16x8*)(qrow + 32 + g * 8);
  const bf16* Kb = qkv + (size_t)tok0 * E3 + koff + qcol;
  const bf16* pmq = pmb + (size_t)(tok0 + q0 + c) * 512;   // q = c (swapped layout)

  float sm = 0.f;
  f32x4 oT[4] = {};

  for (int kt = 0; kt < 512; kt += 64) {
    f32x4 s[4] = {};
    __builtin_amdgcn_s_setprio(1);
#pragma unroll
    for (int j = 0; j < 4; ++j) {
      const bf16* kp = Kb + (size_t)(kt + 16 * j + c) * E3 + g * 8;
      bf16x8 k0 = *(const bf16x8*)kp;
      bf16x8 k1 = *(const bf16x8*)(kp + 32);
      s[j] = MFMA(k0, qf0, s[j]);   // swapped: A=K -> D row=k, col=q
      s[j] = MFMA(k1, qf1, s[j]);
    }
    __builtin_amdgcn_s_setprio(0);
#pragma unroll
    for (int j = 0; j < 4; ++j) {
      bf16x4 e;
      float a0 = s[j][0] * scale, a1 = s[j][1] * scale;
      float a2 = s[j][2] * scale, a3 = s[j][3] * scale;
      if (bias) {
        bf16x4 bb = *(const bf16x4*)(pmq + kt + 16 * j + 4 * g);
        a0 += (float)bb[0]; a1 += (float)bb[1];
        a2 += (float)bb[2]; a3 += (float)bb[3];
      }
      float x0 = __expf(a0), x1 = __expf(a1);
      float x2 = __expf(a2), x3 = __expf(a3);
      sm += (x0 + x1) + (x2 + x3);
      e[0] = (bf16)x0; e[1] = (bf16)x1; e[2] = (bf16)x2; e[3] = (bf16)x3;
      *(bf16x4*)&P_lds[j >> 1][c][(j & 1) * 16 + 4 * g] = e;
    }
    asm volatile("s_waitcnt lgkmcnt(0)" ::: "memory");
    __builtin_amdgcn_s_setprio(1);
#pragma unroll
    for (int hf = 0; hf < 2; ++hf) {
      bf16x8 pf = *(const bf16x8*)&P_lds[hf][c][g * 8];
#pragma unroll
      for (int dt = 0; dt < 4; ++dt) {
        const bf16* vp = Vt + (size_t)(qcol + dt * 16 + c) * 4096
                       + tok0 + kt + hf * 32 + g * 8;
        bf16x8 vf = *(const bf16x8*)vp;
        oT[dt] = MFMA(vf, pf, oT[dt]);
      }
    }
    __builtin_amdgcn_s_setprio(0);
  }

  sm += __shfl_xor(sm, 16);
  sm += __shfl_xor(sm, 32);
  const float inv = 1.0f / sm;
#pragma unroll
  for (int dt = 0; dt < 4; ++dt) {
    bf16x4 o4;
#pragma unroll
    for (int r = 0; r < 4; ++r) o4[r] = (bf16)(oT[dt][r] * inv);
    *(bf16x4*)(out + (size_t)(tok0 + q0 + c) * 640 + colOff + qcol + dt * 16 + 4 * g) = o4;
  }
}

// LayerNorm over D=640, one wave per row, bf16 out.
__global__ __launch_bounds__(256) void ln_kernel(
    const float* __restrict__ x, const float* __restrict__ sca,
    const float* __restrict__ bia, bf16* __restrict__ out)
{
  const int w = threadIdx.x >> 6, l = threadIdx.x & 63;
  const int row = blockIdx.x * 4 + w;
  const float* xr = x + (size_t)row * 640;
  float v[10], sum = 0.f, sq = 0.f;
#pragma unroll
  for (int i = 0; i < 10; ++i) {
    v[i] = xr[l + 64 * i];
    sum += v[i]; sq += v[i] * v[i];
  }
#pragma unroll
  for (int m = 1; m <= 32; m <<= 1) {
    sum += __shfl_xor(sum, m);
    sq  += __shfl_xor(sq, m);
  }
  const float mean = sum * (1.f / 640.f);
  const float var  = sq * (1.f / 640.f) - mean * mean;
  const float rstd = rsqrtf(var + 1e-5f);
  bf16* orow = out + (size_t)row * 640;
#pragma unroll
  for (int i = 0; i < 10; ++i) {
    const int c = l + 64 * i;
    orow[c] = (bf16)((v[i] - mean) * rstd * sca[c] + bia[c]);
  }
}

__global__ void cvt_bf16_k(const float* __restrict__ src, bf16* __restrict__ dst,
                           int perL, int dstStride, int dstOff, int total, float scl)
{
  int i = blockIdx.x * 256 + threadIdx.x;
  if (i >= total) return;
  int l = i / perL, j = i - l * perL;
  dst[(size_t)l * dstStride + dstOff + j] = (bf16)(scl * src[i]);
}

__global__ void cvt_f32_k(const float* __restrict__ src, float* __restrict__ dst,
                          int perL, int dstStride, int dstOff, int total)
{
  int i = blockIdx.x * 256 + threadIdx.x;
  if (i >= total) return;
  int l = i / perL, j = i - l * perL;
  dst[(size_t)l * dstStride + dstOff + j] = src[i];
}

__global__ void tcvt_k(const float* __restrict__ src, bf16* __restrict__ dst,
                       int R, int C)
{
  __shared__ float t[32][33];
  const int lz = blockIdx.z;
  src += (size_t)lz * R * C;
  dst += (size_t)lz * R * C;
  const int c0 = blockIdx.x * 32, r0 = blockIdx.y * 32;
  const int tx = threadIdx.x & 31, ty = threadIdx.x >> 5;
#pragma unroll
  for (int i = ty; i < 32; i += 8)
    t[i][tx] = src[(size_t)(r0 + i) * C + c0 + tx];
  __syncthreads();
#pragma unroll
  for (int i = ty; i < 32; i += 8)
    dst[(size_t)(c0 + i) * R + r0 + tx] = (bf16)t[tx][i];
}

__global__ void biasmix_k(const float* __restrict__ b2, int b2S,
                          const float* __restrict__ W2, long long w2S, int ldw,
                          const float* __restrict__ b1, int b1S,
                          float* __restrict__ dst, int dstS, int dstOff,
                          int M, int K)
{
  const int lz = blockIdx.y;
  const int w = threadIdx.x >> 6, lane = threadIdx.x & 63;
  const int m = blockIdx.x * 4 + w;
  if (m >= M) return;
  const float* wr = W2 + (size_t)lz * w2S + (size_t)m * ldw;
  const float* br = b1 + (size_t)lz * b1S;
  float s = 0.f;
  for (int k = lane; k < K; k += 64) s += wr[k] * br[k];
#pragma unroll
  for (int msk = 1; msk <= 32; msk <<= 1) s += __shfl_xor(s, msk);
  if (lane == 0)
    dst[(size_t)lz * dstS + dstOff + m] = s + b2[(size_t)lz * b2S + m];
}

__global__ void copy_f32(const float* __restrict__ src, float* __restrict__ dst, int n)
{
  int i = blockIdx.x * 256 + threadIdx.x;
  if (i < n) dst[i] = src[i];
}

extern "C" void kernel_launch(void* const* d_in, const int* in_sizes, int n_in,
                              void* d_out, int out_size, void* d_ws, size_t ws_size,
                              hipStream_t stream)
{
  (void)in_sizes; (void)n_in; (void)ws_size;
  const float* src    = (const float*)d_in[0];
  const float* pmask  = (const float*)d_in[1];
  const float* n1_s   = (const float*)d_in[3];
  const float* n1_b   = (const float*)d_in[4];
  const float* pin_W  = (const float*)d_in[5];
  const float* pin_b  = (const float*)d_in[6];
  const float* sin_W  = (const float*)d_in[7];
  const float* sin_b  = (const float*)d_in[8];
  const float* tin_W  = (const float*)d_in[9];
  const float* tin_b  = (const float*)d_in[10];
  const float* pqkv_W = (const float*)d_in[11];
  const float* pqkv_b = (const float*)d_in[12];
  const float* pout_W = (const float*)d_in[13];
  const float* pout_b = (const float*)d_in[14];
  const float* sqkv_W = (const float*)d_in[15];
  const float* sqkv_b = (const float*)d_in[16];
  const float* sout_W = (const float*)d_in[17];
  const float* sout_b = (const float*)d_in[18];
  const float* tqkv_W = (const float*)d_in[19];
  const float* tqkv_b = (const float*)d_in[20];
  const float* tout_W = (const float*)d_in[21];
  const float* tout_b = (const float*)d_in[22];
  const float* o_W    = (const float*)d_in[23];
  const float* o_b    = (const float*)d_in[24];
  const float* ff1_W  = (const float*)d_in[25];
  const float* ff1_b  = (const float*)d_in[26];
  const float* ff2_W  = (const float*)d_in[27];
  const float* ff2_b  = (const float*)d_in[28];
  const float* n2_s   = (const float*)d_in[29];
  const float* n2_b   = (const float*)d_in[30];

  char* wsp = (char*)d_ws;
  auto alloc = [&](size_t bytes) {
    char* p = wsp;
    wsp += (bytes + 255) & ~(size_t)255;
    return p;
  };
  bf16*  Wbig   = (bf16*)alloc(6ull * 1920 * 640 * 2);
  float* bbig   = (float*)alloc(6ull * 1920 * 4);
  bf16*  Weff   = (bf16*)alloc(6ull * 640 * 640 * 2);
  float* beff   = (float*)alloc(6ull * 640 * 4);
  float* catb   = (float*)alloc(6ull * 640 * 4);
  bf16*  Wf1    = (bf16*)alloc(6ull * 2048 * 640 * 2);
  bf16*  Wf2    = (bf16*)alloc(6ull * 2048 * 640 * 2);
  bf16*  xn     = (bf16*)alloc(4096ull * 640 * 2);
  bf16*  Vtp    = (bf16*)alloc(256ull * 4096 * 2);
  bf16*  Vts    = (bf16*)alloc(256ull * 4096 * 2);
  bf16*  Vtt    = (bf16*)alloc(128ull * 4096 * 2);
  bf16*  ao     = (bf16*)alloc(4096ull * 640 * 2);
  bf16*  pmb    = (bf16*)alloc(8ull * 512 * 512 * 2);
  char*  region = alloc(4096ull * 1920 * 2 + 4096ull * 2048 * 2);
  bf16*  qkv    = (bf16*)region;
  bf16*  hbuf   = (bf16*)(region + 4096ull * 1920 * 2);
  char* pr = region;
  auto palloc = [&](size_t bytes) {
    char* p = pr;
    pr += (bytes + 255) & ~(size_t)255;
    return p;
  };
  bf16* Wpq  = (bf16*)palloc(6ull * 768 * 256 * 2);
  bf16* Wsq  = (bf16*)palloc(6ull * 768 * 256 * 2);
  bf16* Wtq  = (bf16*)palloc(6ull * 384 * 128 * 2);
  bf16* pinT = (bf16*)palloc(6ull * 640 * 256 * 2);
  bf16* sinT = (bf16*)palloc(6ull * 640 * 256 * 2);
  bf16* tinT = (bf16*)palloc(6ull * 640 * 128 * 2);
  bf16* Wobf = (bf16*)palloc(6ull * 640 * 640 * 2);
  bf16* WpoT = (bf16*)palloc(6ull * 256 * 256 * 2);
  bf16* WsoT = (bf16*)palloc(6ull * 256 * 256 * 2);
  bf16* WtoT = (bf16*)palloc(6ull * 128 * 128 * 2);

  float* x = (float*)d_out;

  auto cvt = [&](const float* s, bf16* d, int perL) {
    int total = 6 * perL;
    cvt_bf16_k<<<(total + 255) / 256, 256, 0, stream>>>(s, d, perL, perL, 0, total, 1.f);
  };
  cvt(pqkv_W, Wpq, 768 * 256);
  cvt(sqkv_W, Wsq, 768 * 256);
  cvt(tqkv_W, Wtq, 384 * 128);
  cvt(o_W,    Wobf, 640 * 640);
  cvt(ff1_W,  Wf1, 2048 * 640);
  cvt(ff2_W,  Wf2, 2048 * 640);
  {
    int total = 8 * 512 * 512;
    cvt_bf16_k<<<(total + 255) / 256, 256, 0, stream>>>(pmask, pmb, total, total, 0, total, 2.f);
  }
  tcvt_k<<<dim3(20, 8, 6), 256, 0, stream>>>(pin_W, pinT, 256, 640);
  tcvt_k<<<dim3(20, 8, 6), 256, 0, stream>>>(sin_W, sinT, 256, 640);
  tcvt_k<<<dim3(20, 4, 6), 256, 0, stream>>>(tin_W, tinT, 128, 640);
  tcvt_k<<<dim3(8, 8, 6), 256, 0, stream>>>(pout_W, WpoT, 256, 256);
  tcvt_k<<<dim3(8, 8, 6), 256, 0, stream>>>(sout_W, WsoT, 256, 256);
  tcvt_k<<<dim3(4, 4, 6), 256, 0, stream>>>(tout_W, WtoT, 128, 128);
  biasmix_k<<<dim3(192, 6), 256, 0, stream>>>(pqkv_b, 768, pqkv_W, 768 * 256, 256,
                                              pin_b, 256, bbig, 1920, 0, 768, 256);
  biasmix_k<<<dim3(192, 6), 256, 0, stream>>>(sqkv_b, 768, sqkv_W, 768 * 256, 256,
                                              sin_b, 256, bbig, 1920, 768, 768, 256);
  biasmix_k<<<dim3(96, 6), 256, 0, stream>>>(tqkv_b, 384, tqkv_W, 384 * 128, 128,
                                             tin_b, 128, bbig, 1920, 1536, 384, 128);
  cvt_f32_k<<<dim3(6), 256, 0, stream>>>(pout_b, catb, 256, 640, 0,   6 * 256);
  cvt_f32_k<<<dim3(6), 256, 0, stream>>>(sout_b, catb, 256, 640, 256, 6 * 256);
  cvt_f32_k<<<dim3(3), 256, 0, stream>>>(tout_b, catb, 128, 640, 512, 6 * 128);
  biasmix_k<<<dim3(160, 6), 256, 0, stream>>>(o_b, 640, o_W, 640 * 640, 640,
                                              catb, 640, beff, 640, 0, 640, 640);
  gemm_bt<0><<<dim3(5, 6, 6), 256, 0, stream>>>(Wpq, 256, 768 * 256, pinT, 640 * 256,
      nullptr, Wbig, 640, 1920 * 640, 256);
  gemm_bt<0><<<dim3(5, 6, 6), 256, 0, stream>>>(Wsq, 256, 768 * 256, sinT, 640 * 256,
      nullptr, Wbig + 768 * 640, 640, 1920 * 640, 256);
  gemm_bt<0><<<dim3(5, 3, 6), 256, 0, stream>>>(Wtq, 128, 384 * 128, tinT, 640 * 128,
      nullptr, Wbig + 1536 * 640, 640, 1920 * 640, 128);
  gemm_bt<0><<<dim3(2, 5, 6), 256, 0, stream>>>(Wobf, 640, 640 * 640, WpoT, 256 * 256,
      nullptr, Weff, 640, 640 * 640, 256);
  gemm_bt<0><<<dim3(2, 5, 6), 256, 0, stream>>>(Wobf + 256, 640, 640 * 640, WsoT, 256 * 256,
      nullptr, Weff + 256, 640, 640 * 640, 256);
  gemm_bt<0><<<dim3(1, 5, 6), 256, 0, stream>>>(Wobf + 512, 640, 640 * 640, WtoT, 128 * 128,
      nullptr, Weff + 512, 640, 640 * 640, 128);

  copy_f32<<<(out_size + 255) / 256, 256, 0, stream>>>(src, x, out_size);

  for (int l = 0; l < 6; ++l) {
    ln_kernel<<<1024, 256, 0, stream>>>(x, n1_s + l * 640, n1_b + l * 640, xn);
    gemm_h64<3, 1><<<dim3(15, 64), 256, 0, stream>>>(xn, 640,
        Wbig + (size_t)l * 1920 * 640, 640, bbig + l * 1920,
        qkv, 1920, 640, Vtp, Vts, Vtt);
    attn_full<<<2560, 64, 0, stream>>>(qkv, Vtp, Vts, Vtt, pmb, ao);
    gemm_h64<2, 2><<<dim3(5, 64, 2), 256, 0, stream>>>(ao, 640,
        Weff + (size_t)l * 640 * 640, 640, beff + l * 640,
        x, 640, 640, nullptr, nullptr, nullptr);
    ln_kernel<<<1024, 256, 0, stream>>>(x, n2_s + l * 640, n2_b + l * 640, xn);
    gemm_h64<1, 1><<<dim3(16, 64), 256, 0, stream>>>(xn, 640,
        Wf1 + (size_t)l * 2048 * 640, 640, ff1_b + l * 2048,
        hbuf, 2048, 640, nullptr, nullptr, nullptr);
    gemm_h64<2, 4><<<dim3(5, 64, 4), 256, 0, stream>>>(hbuf, 2048,
        Wf2 + (size_t)l * 2048 * 640, 2048, ff2_b + l * 640,
        x, 640, 2048, nullptr, nullptr, nullptr);
  }
}

// Round 17
// 928.481 us; speedup vs baseline: 1.2939x; 1.1670x over previous
//
#include <hip/hip_runtime.h>
#include <hip/hip_bf16.h>
#include <cstdint>

// R16: attn with block-shared K/V LDS staging (4 waves share one glds16-staged
// 64-key tile; pre-swizzled source, XOR-chunk reads). Amortizes the 16-way
// address-divergent loads 4x. Rest = R15 (measured best).

typedef __bf16 bf16;
typedef __bf16 bf16x4 __attribute__((ext_vector_type(4)));
typedef __bf16 bf16x8 __attribute__((ext_vector_type(8)));
typedef float  f32x4  __attribute__((ext_vector_type(4)));

__device__ __forceinline__ void glds16(const void* g, void* l) {
  __builtin_amdgcn_global_load_lds(
      (const __attribute__((address_space(1))) void*)g,
      (__attribute__((address_space(3))) void*)l, 16, 0, 0);
}

#define MFMA(a, b, c) __builtin_amdgcn_mfma_f32_16x16x32_bf16((a), (b), (c), 0, 0, 0)

// ---------------- prep GEMM (m97-style 128x128, BK=32) ----------------
template<int EPI>
__global__ __launch_bounds__(256) void gemm_bt(
    const bf16* __restrict__ A, int lda, long long strideA,
    const bf16* __restrict__ W, long long strideW,
    const float* __restrict__ bias,
    void* __restrict__ Cv, int ldc, long long strideC, int K)
{
  __shared__ bf16 As[128 * 32];
  __shared__ bf16 Ws[128 * 32];
  const int tid = threadIdx.x;
  const int w = tid >> 6;
  const int l = tid & 63;

  const int nwg = gridDim.x * gridDim.y;
  const int orig = blockIdx.x + gridDim.x * blockIdx.y;
  const int q8 = nwg >> 3, r8 = nwg & 7;
  const int xcd = orig & 7, rem = orig >> 3;
  const int wgid = (xcd < r8 ? xcd * (q8 + 1) : r8 * (q8 + 1) + (xcd - r8) * q8) + rem;
  const int bx = wgid % gridDim.x;
  const int by = wgid / gridDim.x;

  const int z = blockIdx.z;
  A += (size_t)z * strideA;
  W += (size_t)z * strideW;

  const int rowBase = by * 128;
  const int colBase = bx * 128;
  const int wr = w >> 1, wc = w & 1;

  f32x4 acc[4][4] = {};

  const bf16* a0 = A + (size_t)(rowBase +      (tid >> 2)) * lda + (tid & 3) * 8;
  const bf16* a1 = A + (size_t)(rowBase + 64 + (tid >> 2)) * lda + (tid & 3) * 8;
  const bf16* w0 = W + (size_t)(colBase +      (tid >> 2)) * K   + (tid & 3) * 8;
  const bf16* w1 = W + (size_t)(colBase + 64 + (tid >> 2)) * K   + (tid & 3) * 8;
  bf16* lA0 = &As[w * 512];
  bf16* lA1 = &As[w * 512 + 2048];
  bf16* lW0 = &Ws[w * 512];
  bf16* lW1 = &Ws[w * 512 + 2048];

  const int arow = wr * 64 + (l & 15);
  const int brow = wc * 64 + (l & 15);
  const int koff = (l >> 4) * 8;

  for (int kt = 0; kt < K; kt += 32) {
    if (kt) __syncthreads();
    glds16(a0, lA0); glds16(a1, lA1);
    glds16(w0, lW0); glds16(w1, lW1);
    a0 += 32; a1 += 32; w0 += 32; w1 += 32;
    __syncthreads();
    bf16x8 af[4], bw[4];
#pragma unroll
    for (int m = 0; m < 4; ++m)
      af[m] = *(const bf16x8*)&As[(arow + m * 16) * 32 + koff];
#pragma unroll
    for (int n = 0; n < 4; ++n)
      bw[n] = *(const bf16x8*)&Ws[(brow + n * 16) * 32 + koff];
#pragma unroll
    for (int m = 0; m < 4; ++m)
#pragma unroll
      for (int n = 0; n < 4; ++n)
        acc[m][n] = MFMA(af[m], bw[n], acc[m][n]);
  }

#pragma unroll
  for (int m = 0; m < 4; ++m) {
#pragma unroll
    for (int n = 0; n < 4; ++n) {
      const int r0  = rowBase + wr * 64 + m * 16 + (l >> 4) * 4;
      const int col = colBase + wc * 64 + n * 16 + (l & 15);
      bf16* C = (bf16*)Cv + (size_t)z * strideC;
#pragma unroll
      for (int r = 0; r < 4; ++r)
        C[(size_t)(r0 + r) * ldc + col] = (bf16)acc[m][n][r];
    }
  }
}

// ---------------- in-loop GEMM: 64x128 tile, BK=64, swizzled LDS ----------------
template<int EPI, int SPLITK>
__global__ __launch_bounds__(256) void gemm_h64(
    const bf16* __restrict__ A, int lda,
    const bf16* __restrict__ W, int ldw,
    const float* __restrict__ bias,
    void* __restrict__ Cv, int ldc, int K,
    bf16* __restrict__ Vtp, bf16* __restrict__ Vts, bf16* __restrict__ Vtt)
{
  __shared__ bf16 As[64 * 64];
  __shared__ bf16 Ws[128 * 64];
  const int tid = threadIdx.x;
  const int w = tid >> 6, l = tid & 63;

  const int nwg = gridDim.x * gridDim.y;
  const int orig = blockIdx.x + gridDim.x * blockIdx.y;
  const int q8 = nwg >> 3, r8 = nwg & 7;
  const int xcd = orig & 7, rem = orig >> 3;
  const int wgid = (xcd < r8 ? xcd * (q8 + 1) : r8 * (q8 + 1) + (xcd - r8) * q8) + rem;
  const int bx = wgid % gridDim.x;
  const int by = wgid / gridDim.x;

  const int rowBase = by * 64, colBase = bx * 128;
  const int Kper = K / SPLITK;
  const int kz = blockIdx.z;

  f32x4 acc[4][2] = {};

  const bf16* aSrc[2];
  const bf16* wSrc[4];
#pragma unroll
  for (int i = 0; i < 2; ++i) {
    int ci = i * 256 + tid, row = ci >> 3, k8 = ci & 7;
    aSrc[i] = A + (size_t)(rowBase + row) * lda + kz * Kper + ((k8 ^ (row & 7)) << 3);
  }
#pragma unroll
  for (int i = 0; i < 4; ++i) {
    int ci = i * 256 + tid, row = ci >> 3, k8 = ci & 7;
    wSrc[i] = W + (size_t)(colBase + row) * ldw + kz * Kper + ((k8 ^ (row & 7)) << 3);
  }
  bf16* aDst[2] = { &As[w * 512], &As[2048 + w * 512] };
  bf16* wDst[4] = { &Ws[w * 512], &Ws[2048 + w * 512],
                    &Ws[4096 + w * 512], &Ws[6144 + w * 512] };

  const int c15 = l & 15, g = l >> 4;

  for (int kt = 0; kt < Kper; kt += 64) {
    if (kt) __syncthreads();
    glds16(aSrc[0], aDst[0]); glds16(aSrc[1], aDst[1]);
#pragma unroll
    for (int i = 0; i < 4; ++i) glds16(wSrc[i], wDst[i]);
    aSrc[0] += 64; aSrc[1] += 64;
#pragma unroll
    for (int i = 0; i < 4; ++i) wSrc[i] += 64;
    __syncthreads();
#pragma unroll
    for (int kh = 0; kh < 2; ++kh) {
      const int ks = g + 4 * kh;
      bf16x8 af[4], bw[2];
#pragma unroll
      for (int m = 0; m < 4; ++m) {
        const int row = c15 + m * 16;
        af[m] = *(const bf16x8*)&As[row * 64 + ((ks ^ (row & 7)) << 3)];
      }
#pragma unroll
      for (int n = 0; n < 2; ++n) {
        const int row = w * 32 + n * 16 + c15;
        bw[n] = *(const bf16x8*)&Ws[row * 64 + ((ks ^ (row & 7)) << 3)];
      }
#pragma unroll
      for (int m = 0; m < 4; ++m)
#pragma unroll
        for (int n = 0; n < 2; ++n)
          acc[m][n] = MFMA(af[m], bw[n], acc[m][n]);
    }
  }

#pragma unroll
  for (int m = 0; m < 4; ++m) {
#pragma unroll
    for (int n = 0; n < 2; ++n) {
      const int r0  = rowBase + m * 16 + g * 4;
      const int col = colBase + w * 32 + n * 16 + c15;
      const float bv = bias[col];
      if (EPI == 2) {
        float* C = (float*)Cv;
        const float badd = (SPLITK == 1 || kz == 0) ? bv : 0.f;
#pragma unroll
        for (int r = 0; r < 4; ++r)
          atomicAdd(&C[(size_t)(r0 + r) * ldc + col], acc[m][n][r] + badd);
      } else if (EPI == 3) {
        bf16* vdst = nullptr;
        if (col >= 512 && col < 768)        vdst = Vtp + (size_t)(col - 512)  * 4096;
        else if (col >= 1280 && col < 1536) vdst = Vts + (size_t)(col - 1280) * 4096;
        else if (col >= 1792)               vdst = Vtt + (size_t)(col - 1792) * 4096;
        if (vdst) {
          bf16x4 o4;
#pragma unroll
          for (int r = 0; r < 4; ++r) o4[r] = (bf16)(acc[m][n][r] + bv);
          *(bf16x4*)(vdst + r0) = o4;
        } else {
          bf16* C = (bf16*)Cv;
#pragma unroll
          for (int r = 0; r < 4; ++r)
            C[(size_t)(r0 + r) * ldc + col] = (bf16)(acc[m][n][r] + bv);
        }
      } else {
        bf16* C = (bf16*)Cv;
#pragma unroll
        for (int r = 0; r < 4; ++r) {
          float v = acc[m][n][r] + bv;
          if (EPI == 1) v = fmaxf(v, 0.f);
          C[(size_t)(r0 + r) * ldc + col] = (bf16)v;
        }
      }
    }
  }
}

// ---------------- attention: swapped-QK, no-max exp, shared K/V LDS staging ----------------
// 640 blocks x 4 waves; block stages the 64-key K and V tiles once per iter
// (16 glds16, pre-swizzled source), waves read XOR-swizzled fragments from LDS.
__global__ __launch_bounds__(256) void attn_full(
    const bf16* __restrict__ qkv,
    const bf16* __restrict__ Vtp, const bf16* __restrict__ Vts,
    const bf16* __restrict__ Vtt,
    const bf16* __restrict__ pmb, bf16* __restrict__ out)
{
  __shared__ __align__(16) bf16 Ks[64 * 64];            // 8 KB, chunk-swizzled
  __shared__ __align__(16) bf16 Vs[64 * 64];            // 8 KB
  __shared__ __align__(16) bf16 P_lds[4][2][16][40];    // 10 KB
  const int orig = blockIdx.x;                 // 640 = 8 XCD * 80
  const int bid = (orig & 7) * 80 + (orig >> 3);
  const bf16* Vt; int qoff, koff, colOff; bool bias;
  int b, h, qblk;
  if (bid < 256) {
    Vt = Vtp; qoff = 0; koff = 256; colOff = 0; bias = false;
    b = bid >> 5; h = (bid >> 3) & 3; qblk = bid & 7;
  } else if (bid < 512) {
    int i = bid - 256;
    Vt = Vts; qoff = 768; koff = 1024; colOff = 256; bias = true;
    b = i >> 5; h = (i >> 3) & 3; qblk = i & 7;
  } else {
    int i = bid - 512;
    Vt = Vtt; qoff = 1536; koff = 1664; colOff = 512; bias = false;
    b = i >> 4; h = (i >> 3) & 1; qblk = i & 7;
  }
  const int E3 = 1920;
  const int qcol = h * 64;
  const int tid = threadIdx.x;
  const int w = tid >> 6, l = tid & 63;
  const int g = l >> 4, c = l & 15;
  const int q0 = qblk * 64 + w * 16;
  const int tok0 = b * 512;
  const float scale = 0.125f;

  const bf16* qrow = qkv + (size_t)(tok0 + q0 + c) * E3 + qoff + qcol;
  bf16x8 qf0 = *(const bf16x8*)(qrow + g * 8);
  bf16x8 qf1 = *(const bf16x8*)(qrow + 32 + g * 8);
  const bf16* Kb = qkv + (size_t)tok0 * E3 + koff + qcol;
  const bf16* pmq = pmb + (size_t)(tok0 + q0 + c) * 512;   // q = c (swapped layout)

  // staging: chunk ci -> row=ci>>3 (key or d), chunk=ci&7 within 128B row,
  // source chunk pre-swizzled (chunk ^ (row&7)); LDS dest linear (glds16).
  const int ciA = tid, ciB = 256 + tid;
  const int rA = ciA >> 3, cA = ciA & 7;
  const int rB = ciB >> 3, cB = ciB & 7;
  const bf16* kSrcA = Kb + (size_t)rA * E3 + ((cA ^ (rA & 7)) << 3);
  const bf16* kSrcB = Kb + (size_t)rB * E3 + ((cB ^ (rB & 7)) << 3);
  const bf16* vSrcA = Vt + (size_t)(qcol + rA) * 4096 + tok0 + ((cA ^ (rA & 7)) << 3);
  const bf16* vSrcB = Vt + (size_t)(qcol + rB) * 4096 + tok0 + ((cB ^ (rB & 7)) << 3);
  bf16* kDstA = &Ks[(size_t)w * 512];
  bf16* kDstB = &Ks[2048 + (size_t)w * 512];
  bf16* vDstA = &Vs[(size_t)w * 512];
  bf16* vDstB = &Vs[2048 + (size_t)w * 512];

  float sm = 0.f;
  f32x4 oT[4] = {};
  const int cx = c & 7;

  for (int it = 0; it < 8; ++it) {
    const int kt = it * 64;
    if (it) __syncthreads();                 // protect tiles from overwrite
    glds16(kSrcA, kDstA); glds16(kSrcB, kDstB);
    glds16(vSrcA, vDstA); glds16(vSrcB, vDstB);
    kSrcA += (size_t)64 * E3; kSrcB += (size_t)64 * E3;
    vSrcA += 64; vSrcB += 64;
    __syncthreads();                         // tiles ready (vmcnt drained)

    // ---- QK from LDS: 8 MFMAs ----
    f32x4 s[4] = {};
    __builtin_amdgcn_s_setprio(1);
#pragma unroll
    for (int j = 0; j < 4; ++j) {
      const int row = 16 * j + c;
      bf16x8 k0 = *(const bf16x8*)&Ks[row * 64 + ((g ^ cx) << 3)];
      bf16x8 k1 = *(const bf16x8*)&Ks[row * 64 + (((4 + g) ^ cx) << 3)];
      s[j] = MFMA(k0, qf0, s[j]);   // swapped: A=K -> D row=k, col=q
      s[j] = MFMA(k1, qf1, s[j]);
    }
    __builtin_amdgcn_s_setprio(0);
    // ---- exp (no max-sub; bounded), pack, P write ----
#pragma unroll
    for (int j = 0; j < 4; ++j) {
      bf16x4 e;
      float a0 = s[j][0] * scale, a1 = s[j][1] * scale;
      float a2 = s[j][2] * scale, a3 = s[j][3] * scale;
      if (bias) {
        bf16x4 bb = *(const bf16x4*)(pmq + kt + 16 * j + 4 * g);
        a0 += (float)bb[0]; a1 += (float)bb[1];
        a2 += (float)bb[2]; a3 += (float)bb[3];
      }
      float x0 = __expf(a0), x1 = __expf(a1);
      float x2 = __expf(a2), x3 = __expf(a3);
      sm += (x0 + x1) + (x2 + x3);
      e[0] = (bf16)x0; e[1] = (bf16)x1; e[2] = (bf16)x2; e[3] = (bf16)x3;
      *(bf16x4*)&P_lds[w][j >> 1][c][(j & 1) * 16 + 4 * g] = e;
    }
    asm volatile("s_waitcnt lgkmcnt(0)" ::: "memory");
    // ---- PV from LDS: 8 MFMAs ----
    __builtin_amdgcn_s_setprio(1);
#pragma unroll
    for (int hf = 0; hf < 2; ++hf) {
      bf16x8 pf = *(const bf16x8*)&P_lds[w][hf][c][g * 8];
#pragma unroll
      for (int dt = 0; dt < 4; ++dt) {
        const int vrow = dt * 16 + c;
        bf16x8 vf = *(const bf16x8*)&Vs[vrow * 64 + (((hf * 4 + g) ^ cx) << 3)];
        oT[dt] = MFMA(vf, pf, oT[dt]);
      }
    }
    __builtin_amdgcn_s_setprio(0);
  }

  // full row-sum for q=c: reduce over the 4 lanes sharing c
  sm += __shfl_xor(sm, 16);
  sm += __shfl_xor(sm, 32);
  const float inv = 1.0f / sm;
#pragma unroll
  for (int dt = 0; dt < 4; ++dt) {
    bf16x4 o4;
#pragma unroll
    for (int r = 0; r < 4; ++r) o4[r] = (bf16)(oT[dt][r] * inv);
    *(bf16x4*)(out + (size_t)(tok0 + q0 + c) * 640 + colOff + qcol + dt * 16 + 4 * g) = o4;
  }
}

// LayerNorm over D=640, one wave per row, bf16 out.
__global__ __launch_bounds__(256) void ln_kernel(
    const float* __restrict__ x, const float* __restrict__ sca,
    const float* __restrict__ bia, bf16* __restrict__ out)
{
  const int w = threadIdx.x >> 6, l = threadIdx.x & 63;
  const int row = blockIdx.x * 4 + w;
  const float* xr = x + (size_t)row * 640;
  float v[10], sum = 0.f, sq = 0.f;
#pragma unroll
  for (int i = 0; i < 10; ++i) {
    v[i] = xr[l + 64 * i];
    sum += v[i]; sq += v[i] * v[i];
  }
#pragma unroll
  for (int m = 1; m <= 32; m <<= 1) {
    sum += __shfl_xor(sum, m);
    sq  += __shfl_xor(sq, m);
  }
  const float mean = sum * (1.f / 640.f);
  const float var  = sq * (1.f / 640.f) - mean * mean;
  const float rstd = rsqrtf(var + 1e-5f);
  bf16* orow = out + (size_t)row * 640;
#pragma unroll
  for (int i = 0; i < 10; ++i) {
    const int c = l + 64 * i;
    orow[c] = (bf16)((v[i] - mean) * rstd * sca[c] + bia[c]);
  }
}

__global__ void cvt_bf16_k(const float* __restrict__ src, bf16* __restrict__ dst,
                           int perL, int dstStride, int dstOff, int total, float scl)
{
  int i = blockIdx.x * 256 + threadIdx.x;
  if (i >= total) return;
  int l = i / perL, j = i - l * perL;
  dst[(size_t)l * dstStride + dstOff + j] = (bf16)(scl * src[i]);
}

__global__ void cvt_f32_k(const float* __restrict__ src, float* __restrict__ dst,
                          int perL, int dstStride, int dstOff, int total)
{
  int i = blockIdx.x * 256 + threadIdx.x;
  if (i >= total) return;
  int l = i / perL, j = i - l * perL;
  dst[(size_t)l * dstStride + dstOff + j] = src[i];
}

__global__ void tcvt_k(const float* __restrict__ src, bf16* __restrict__ dst,
                       int R, int C)
{
  __shared__ float t[32][33];
  const int lz = blockIdx.z;
  src += (size_t)lz * R * C;
  dst += (size_t)lz * R * C;
  const int c0 = blockIdx.x * 32, r0 = blockIdx.y * 32;
  const int tx = threadIdx.x & 31, ty = threadIdx.x >> 5;
#pragma unroll
  for (int i = ty; i < 32; i += 8)
    t[i][tx] = src[(size_t)(r0 + i) * C + c0 + tx];
  __syncthreads();
#pragma unroll
  for (int i = ty; i < 32; i += 8)
    dst[(size_t)(c0 + i) * R + r0 + tx] = (bf16)t[tx][i];
}

__global__ void biasmix_k(const float* __restrict__ b2, int b2S,
                          const float* __restrict__ W2, long long w2S, int ldw,
                          const float* __restrict__ b1, int b1S,
                          float* __restrict__ dst, int dstS, int dstOff,
                          int M, int K)
{
  const int lz = blockIdx.y;
  const int w = threadIdx.x >> 6, lane = threadIdx.x & 63;
  const int m = blockIdx.x * 4 + w;
  if (m >= M) return;
  const float* wr = W2 + (size_t)lz * w2S + (size_t)m * ldw;
  const float* br = b1 + (size_t)lz * b1S;
  float s = 0.f;
  for (int k = lane; k < K; k += 64) s += wr[k] * br[k];
#pragma unroll
  for (int msk = 1; msk <= 32; msk <<= 1) s += __shfl_xor(s, msk);
  if (lane == 0)
    dst[(size_t)lz * dstS + dstOff + m] = s + b2[(size_t)lz * b2S + m];
}

__global__ void copy_f32(const float* __restrict__ src, float* __restrict__ dst, int n)
{
  int i = blockIdx.x * 256 + threadIdx.x;
  if (i < n) dst[i] = src[i];
}

extern "C" void kernel_launch(void* const* d_in, const int* in_sizes, int n_in,
                              void* d_out, int out_size, void* d_ws, size_t ws_size,
                              hipStream_t stream)
{
  (void)in_sizes; (void)n_in; (void)ws_size;
  const float* src    = (const float*)d_in[0];
  const float* pmask  = (const float*)d_in[1];
  const float* n1_s   = (const float*)d_in[3];
  const float* n1_b   = (const float*)d_in[4];
  const float* pin_W  = (const float*)d_in[5];
  const float* pin_b  = (const float*)d_in[6];
  const float* sin_W  = (const float*)d_in[7];
  const float* sin_b  = (const float*)d_in[8];
  const float* tin_W  = (const float*)d_in[9];
  const float* tin_b  = (const float*)d_in[10];
  const float* pqkv_W = (const float*)d_in[11];
  const float* pqkv_b = (const float*)d_in[12];
  const float* pout_W = (const float*)d_in[13];
  const float* pout_b = (const float*)d_in[14];
  const float* sqkv_W = (const float*)d_in[15];
  const float* sqkv_b = (const float*)d_in[16];
  const float* sout_W = (const float*)d_in[17];
  const float* sout_b = (const float*)d_in[18];
  const float* tqkv_W = (const float*)d_in[19];
  const float* tqkv_b = (const float*)d_in[20];
  const float* tout_W = (const float*)d_in[21];
  const float* tout_b = (const float*)d_in[22];
  const float* o_W    = (const float*)d_in[23];
  const float* o_b    = (const float*)d_in[24];
  const float* ff1_W  = (const float*)d_in[25];
  const float* ff1_b  = (const float*)d_in[26];
  const float* ff2_W  = (const float*)d_in[27];
  const float* ff2_b  = (const float*)d_in[28];
  const float* n2_s   = (const float*)d_in[29];
  const float* n2_b   = (const float*)d_in[30];

  char* wsp = (char*)d_ws;
  auto alloc = [&](size_t bytes) {
    char* p = wsp;
    wsp += (bytes + 255) & ~(size_t)255;
    return p;
  };
  bf16*  Wbig   = (bf16*)alloc(6ull * 1920 * 640 * 2);
  float* bbig   = (float*)alloc(6ull * 1920 * 4);
  bf16*  Weff   = (bf16*)alloc(6ull * 640 * 640 * 2);
  float* beff   = (float*)alloc(6ull * 640 * 4);
  float* catb   = (float*)alloc(6ull * 640 * 4);
  bf16*  Wf1    = (bf16*)alloc(6ull * 2048 * 640 * 2);
  bf16*  Wf2    = (bf16*)alloc(6ull * 2048 * 640 * 2);
  bf16*  xn     = (bf16*)alloc(4096ull * 640 * 2);
  bf16*  Vtp    = (bf16*)alloc(256ull * 4096 * 2);
  bf16*  Vts    = (bf16*)alloc(256ull * 4096 * 2);
  bf16*  Vtt    = (bf16*)alloc(128ull * 4096 * 2);
  bf16*  ao     = (bf16*)alloc(4096ull * 640 * 2);
  bf16*  pmb    = (bf16*)alloc(8ull * 512 * 512 * 2);
  char*  region = alloc(4096ull * 1920 * 2 + 4096ull * 2048 * 2);
  bf16*  qkv    = (bf16*)region;
  bf16*  hbuf   = (bf16*)(region + 4096ull * 1920 * 2);
  char* pr = region;
  auto palloc = [&](size_t bytes) {
    char* p = pr;
    pr += (bytes + 255) & ~(size_t)255;
    return p;
  };
  bf16* Wpq  = (bf16*)palloc(6ull * 768 * 256 * 2);
  bf16* Wsq  = (bf16*)palloc(6ull * 768 * 256 * 2);
  bf16* Wtq  = (bf16*)palloc(6ull * 384 * 128 * 2);
  bf16* pinT = (bf16*)palloc(6ull * 640 * 256 * 2);
  bf16* sinT = (bf16*)palloc(6ull * 640 * 256 * 2);
  bf16* tinT = (bf16*)palloc(6ull * 640 * 128 * 2);
  bf16* Wobf = (bf16*)palloc(6ull * 640 * 640 * 2);
  bf16* WpoT = (bf16*)palloc(6ull * 256 * 256 * 2);
  bf16* WsoT = (bf16*)palloc(6ull * 256 * 256 * 2);
  bf16* WtoT = (bf16*)palloc(6ull * 128 * 128 * 2);

  float* x = (float*)d_out;

  auto cvt = [&](const float* s, bf16* d, int perL) {
    int total = 6 * perL;
    cvt_bf16_k<<<(total + 255) / 256, 256, 0, stream>>>(s, d, perL, perL, 0, total, 1.f);
  };
  cvt(pqkv_W, Wpq, 768 * 256);
  cvt(sqkv_W, Wsq, 768 * 256);
  cvt(tqkv_W, Wtq, 384 * 128);
  cvt(o_W,    Wobf, 640 * 640);
  cvt(ff1_W,  Wf1, 2048 * 640);
  cvt(ff2_W,  Wf2, 2048 * 640);
  {
    int total = 8 * 512 * 512;
    cvt_bf16_k<<<(total + 255) / 256, 256, 0, stream>>>(pmask, pmb, total, total, 0, total, 2.f);
  }
  tcvt_k<<<dim3(20, 8, 6), 256, 0, stream>>>(pin_W, pinT, 256, 640);
  tcvt_k<<<dim3(20, 8, 6), 256, 0, stream>>>(sin_W, sinT, 256, 640);
  tcvt_k<<<dim3(20, 4, 6), 256, 0, stream>>>(tin_W, tinT, 128, 640);
  tcvt_k<<<dim3(8, 8, 6), 256, 0, stream>>>(pout_W, WpoT, 256, 256);
  tcvt_k<<<dim3(8, 8, 6), 256, 0, stream>>>(sout_W, WsoT, 256, 256);
  tcvt_k<<<dim3(4, 4, 6), 256, 0, stream>>>(tout_W, WtoT, 128, 128);
  biasmix_k<<<dim3(192, 6), 256, 0, stream>>>(pqkv_b, 768, pqkv_W, 768 * 256, 256,
                                              pin_b, 256, bbig, 1920, 0, 768, 256);
  biasmix_k<<<dim3(192, 6), 256, 0, stream>>>(sqkv_b, 768, sqkv_W, 768 * 256, 256,
                                              sin_b, 256, bbig, 1920, 768, 768, 256);
  biasmix_k<<<dim3(96, 6), 256, 0, stream>>>(tqkv_b, 384, tqkv_W, 384 * 128, 128,
                                             tin_b, 128, bbig, 1920, 1536, 384, 128);
  cvt_f32_k<<<dim3(6), 256, 0, stream>>>(pout_b, catb, 256, 640, 0,   6 * 256);
  cvt_f32_k<<<dim3(6), 256, 0, stream>>>(sout_b, catb, 256, 640, 256, 6 * 256);
  cvt_f32_k<<<dim3(3), 256, 0, stream>>>(tout_b, catb, 128, 640, 512, 6 * 128);
  biasmix_k<<<dim3(160, 6), 256, 0, stream>>>(o_b, 640, o_W, 640 * 640, 640,
                                              catb, 640, beff, 640, 0, 640, 640);
  gemm_bt<0><<<dim3(5, 6, 6), 256, 0, stream>>>(Wpq, 256, 768 * 256, pinT, 640 * 256,
      nullptr, Wbig, 640, 1920 * 640, 256);
  gemm_bt<0><<<dim3(5, 6, 6), 256, 0, stream>>>(Wsq, 256, 768 * 256, sinT, 640 * 256,
      nullptr, Wbig + 768 * 640, 640, 1920 * 640, 256);
  gemm_bt<0><<<dim3(5, 3, 6), 256, 0, stream>>>(Wtq, 128, 384 * 128, tinT, 640 * 128,
      nullptr, Wbig + 1536 * 640, 640, 1920 * 640, 128);
  gemm_bt<0><<<dim3(2, 5, 6), 256, 0, stream>>>(Wobf, 640, 640 * 640, WpoT, 256 * 256,
      nullptr, Weff, 640, 640 * 640, 256);
  gemm_bt<0><<<dim3(2, 5, 6), 256, 0, stream>>>(Wobf + 256, 640, 640 * 640, WsoT, 256 * 256,
      nullptr, Weff + 256, 640, 640 * 640, 256);
  gemm_bt<0><<<dim3(1, 5, 6), 256, 0, stream>>>(Wobf + 512, 640, 640 * 640, WtoT, 128 * 128,
      nullptr, Weff + 512, 640, 640 * 640, 128);

  copy_f32<<<(out_size + 255) / 256, 256, 0, stream>>>(src, x, out_size);

  for (int l = 0; l < 6; ++l) {
    ln_kernel<<<1024, 256, 0, stream>>>(x, n1_s + l * 640, n1_b + l * 640, xn);
    gemm_h64<3, 1><<<dim3(15, 64), 256, 0, stream>>>(xn, 640,
        Wbig + (size_t)l * 1920 * 640, 640, bbig + l * 1920,
        qkv, 1920, 640, Vtp, Vts, Vtt);
    attn_full<<<640, 256, 0, stream>>>(qkv, Vtp, Vts, Vtt, pmb, ao);
    gemm_h64<2, 2><<<dim3(5, 64, 2), 256, 0, stream>>>(ao, 640,
        Weff + (size_t)l * 640 * 640, 640, beff + l * 640,
        x, 640, 640, nullptr, nullptr, nullptr);
    ln_kernel<<<1024, 256, 0, stream>>>(x, n2_s + l * 640, n2_b + l * 640, xn);
    gemm_h64<1, 1><<<dim3(16, 64), 256, 0, stream>>>(xn, 640,
        Wf1 + (size_t)l * 2048 * 640, 640, ff1_b + l * 2048,
        hbuf, 2048, 640, nullptr, nullptr, nullptr);
    gemm_h64<2, 4><<<dim3(5, 64, 4), 256, 0, stream>>>(hbuf, 2048,
        Wf2 + (size_t)l * 2048 * 640, 2048, ff2_b + l * 640,
        x, 640, 2048, nullptr, nullptr, nullptr);
  }
}

// Round 18
// 839.480 us; speedup vs baseline: 1.4311x; 1.1060x over previous
//
#include <hip/hip_runtime.h>
#include <hip/hip_bf16.h>
#include <cstdint>

// R17: R16 + ff2 SPLITK 4->2 (atomic RMW traffic 41->20.5 MB/dispatch).
// attn: block-shared K/V LDS staging (R16, big win). Rest identical.

typedef __bf16 bf16;
typedef __bf16 bf16x4 __attribute__((ext_vector_type(4)));
typedef __bf16 bf16x8 __attribute__((ext_vector_type(8)));
typedef float  f32x4  __attribute__((ext_vector_type(4)));

__device__ __forceinline__ void glds16(const void* g, void* l) {
  __builtin_amdgcn_global_load_lds(
      (const __attribute__((address_space(1))) void*)g,
      (__attribute__((address_space(3))) void*)l, 16, 0, 0);
}

#define MFMA(a, b, c) __builtin_amdgcn_mfma_f32_16x16x32_bf16((a), (b), (c), 0, 0, 0)

// ---------------- prep GEMM (m97-style 128x128, BK=32) ----------------
template<int EPI>
__global__ __launch_bounds__(256) void gemm_bt(
    const bf16* __restrict__ A, int lda, long long strideA,
    const bf16* __restrict__ W, long long strideW,
    const float* __restrict__ bias,
    void* __restrict__ Cv, int ldc, long long strideC, int K)
{
  __shared__ bf16 As[128 * 32];
  __shared__ bf16 Ws[128 * 32];
  const int tid = threadIdx.x;
  const int w = tid >> 6;
  const int l = tid & 63;

  const int nwg = gridDim.x * gridDim.y;
  const int orig = blockIdx.x + gridDim.x * blockIdx.y;
  const int q8 = nwg >> 3, r8 = nwg & 7;
  const int xcd = orig & 7, rem = orig >> 3;
  const int wgid = (xcd < r8 ? xcd * (q8 + 1) : r8 * (q8 + 1) + (xcd - r8) * q8) + rem;
  const int bx = wgid % gridDim.x;
  const int by = wgid / gridDim.x;

  const int z = blockIdx.z;
  A += (size_t)z * strideA;
  W += (size_t)z * strideW;

  const int rowBase = by * 128;
  const int colBase = bx * 128;
  const int wr = w >> 1, wc = w & 1;

  f32x4 acc[4][4] = {};

  const bf16* a0 = A + (size_t)(rowBase +      (tid >> 2)) * lda + (tid & 3) * 8;
  const bf16* a1 = A + (size_t)(rowBase + 64 + (tid >> 2)) * lda + (tid & 3) * 8;
  const bf16* w0 = W + (size_t)(colBase +      (tid >> 2)) * K   + (tid & 3) * 8;
  const bf16* w1 = W + (size_t)(colBase + 64 + (tid >> 2)) * K   + (tid & 3) * 8;
  bf16* lA0 = &As[w * 512];
  bf16* lA1 = &As[w * 512 + 2048];
  bf16* lW0 = &Ws[w * 512];
  bf16* lW1 = &Ws[w * 512 + 2048];

  const int arow = wr * 64 + (l & 15);
  const int brow = wc * 64 + (l & 15);
  const int koff = (l >> 4) * 8;

  for (int kt = 0; kt < K; kt += 32) {
    if (kt) __syncthreads();
    glds16(a0, lA0); glds16(a1, lA1);
    glds16(w0, lW0); glds16(w1, lW1);
    a0 += 32; a1 += 32; w0 += 32; w1 += 32;
    __syncthreads();
    bf16x8 af[4], bw[4];
#pragma unroll
    for (int m = 0; m < 4; ++m)
      af[m] = *(const bf16x8*)&As[(arow + m * 16) * 32 + koff];
#pragma unroll
    for (int n = 0; n < 4; ++n)
      bw[n] = *(const bf16x8*)&Ws[(brow + n * 16) * 32 + koff];
#pragma unroll
    for (int m = 0; m < 4; ++m)
#pragma unroll
      for (int n = 0; n < 4; ++n)
        acc[m][n] = MFMA(af[m], bw[n], acc[m][n]);
  }

#pragma unroll
  for (int m = 0; m < 4; ++m) {
#pragma unroll
    for (int n = 0; n < 4; ++n) {
      const int r0  = rowBase + wr * 64 + m * 16 + (l >> 4) * 4;
      const int col = colBase + wc * 64 + n * 16 + (l & 15);
      bf16* C = (bf16*)Cv + (size_t)z * strideC;
#pragma unroll
      for (int r = 0; r < 4; ++r)
        C[(size_t)(r0 + r) * ldc + col] = (bf16)acc[m][n][r];
    }
  }
}

// ---------------- in-loop GEMM: 64x128 tile, BK=64, swizzled LDS ----------------
template<int EPI, int SPLITK>
__global__ __launch_bounds__(256) void gemm_h64(
    const bf16* __restrict__ A, int lda,
    const bf16* __restrict__ W, int ldw,
    const float* __restrict__ bias,
    void* __restrict__ Cv, int ldc, int K,
    bf16* __restrict__ Vtp, bf16* __restrict__ Vts, bf16* __restrict__ Vtt)
{
  __shared__ bf16 As[64 * 64];
  __shared__ bf16 Ws[128 * 64];
  const int tid = threadIdx.x;
  const int w = tid >> 6, l = tid & 63;

  const int nwg = gridDim.x * gridDim.y;
  const int orig = blockIdx.x + gridDim.x * blockIdx.y;
  const int q8 = nwg >> 3, r8 = nwg & 7;
  const int xcd = orig & 7, rem = orig >> 3;
  const int wgid = (xcd < r8 ? xcd * (q8 + 1) : r8 * (q8 + 1) + (xcd - r8) * q8) + rem;
  const int bx = wgid % gridDim.x;
  const int by = wgid / gridDim.x;

  const int rowBase = by * 64, colBase = bx * 128;
  const int Kper = K / SPLITK;
  const int kz = blockIdx.z;

  f32x4 acc[4][2] = {};

  const bf16* aSrc[2];
  const bf16* wSrc[4];
#pragma unroll
  for (int i = 0; i < 2; ++i) {
    int ci = i * 256 + tid, row = ci >> 3, k8 = ci & 7;
    aSrc[i] = A + (size_t)(rowBase + row) * lda + kz * Kper + ((k8 ^ (row & 7)) << 3);
  }
#pragma unroll
  for (int i = 0; i < 4; ++i) {
    int ci = i * 256 + tid, row = ci >> 3, k8 = ci & 7;
    wSrc[i] = W + (size_t)(colBase + row) * ldw + kz * Kper + ((k8 ^ (row & 7)) << 3);
  }
  bf16* aDst[2] = { &As[w * 512], &As[2048 + w * 512] };
  bf16* wDst[4] = { &Ws[w * 512], &Ws[2048 + w * 512],
                    &Ws[4096 + w * 512], &Ws[6144 + w * 512] };

  const int c15 = l & 15, g = l >> 4;

  for (int kt = 0; kt < Kper; kt += 64) {
    if (kt) __syncthreads();
    glds16(aSrc[0], aDst[0]); glds16(aSrc[1], aDst[1]);
#pragma unroll
    for (int i = 0; i < 4; ++i) glds16(wSrc[i], wDst[i]);
    aSrc[0] += 64; aSrc[1] += 64;
#pragma unroll
    for (int i = 0; i < 4; ++i) wSrc[i] += 64;
    __syncthreads();
#pragma unroll
    for (int kh = 0; kh < 2; ++kh) {
      const int ks = g + 4 * kh;
      bf16x8 af[4], bw[2];
#pragma unroll
      for (int m = 0; m < 4; ++m) {
        const int row = c15 + m * 16;
        af[m] = *(const bf16x8*)&As[row * 64 + ((ks ^ (row & 7)) << 3)];
      }
#pragma unroll
      for (int n = 0; n < 2; ++n) {
        const int row = w * 32 + n * 16 + c15;
        bw[n] = *(const bf16x8*)&Ws[row * 64 + ((ks ^ (row & 7)) << 3)];
      }
#pragma unroll
      for (int m = 0; m < 4; ++m)
#pragma unroll
        for (int n = 0; n < 2; ++n)
          acc[m][n] = MFMA(af[m], bw[n], acc[m][n]);
    }
  }

#pragma unroll
  for (int m = 0; m < 4; ++m) {
#pragma unroll
    for (int n = 0; n < 2; ++n) {
      const int r0  = rowBase + m * 16 + g * 4;
      const int col = colBase + w * 32 + n * 16 + c15;
      const float bv = bias[col];
      if (EPI == 2) {
        float* C = (float*)Cv;
        const float badd = (SPLITK == 1 || kz == 0) ? bv : 0.f;
#pragma unroll
        for (int r = 0; r < 4; ++r)
          atomicAdd(&C[(size_t)(r0 + r) * ldc + col], acc[m][n][r] + badd);
      } else if (EPI == 3) {
        bf16* vdst = nullptr;
        if (col >= 512 && col < 768)        vdst = Vtp + (size_t)(col - 512)  * 4096;
        else if (col >= 1280 && col < 1536) vdst = Vts + (size_t)(col - 1280) * 4096;
        else if (col >= 1792)               vdst = Vtt + (size_t)(col - 1792) * 4096;
        if (vdst) {
          bf16x4 o4;
#pragma unroll
          for (int r = 0; r < 4; ++r) o4[r] = (bf16)(acc[m][n][r] + bv);
          *(bf16x4*)(vdst + r0) = o4;
        } else {
          bf16* C = (bf16*)Cv;
#pragma unroll
          for (int r = 0; r < 4; ++r)
            C[(size_t)(r0 + r) * ldc + col] = (bf16)(acc[m][n][r] + bv);
        }
      } else {
        bf16* C = (bf16*)Cv;
#pragma unroll
        for (int r = 0; r < 4; ++r) {
          float v = acc[m][n][r] + bv;
          if (EPI == 1) v = fmaxf(v, 0.f);
          C[(size_t)(r0 + r) * ldc + col] = (bf16)v;
        }
      }
    }
  }
}

// ---------------- attention: swapped-QK, no-max exp, shared K/V LDS staging ----------------
__global__ __launch_bounds__(256) void attn_full(
    const bf16* __restrict__ qkv,
    const bf16* __restrict__ Vtp, const bf16* __restrict__ Vts,
    const bf16* __restrict__ Vtt,
    const bf16* __restrict__ pmb, bf16* __restrict__ out)
{
  __shared__ __align__(16) bf16 Ks[64 * 64];
  __shared__ __align__(16) bf16 Vs[64 * 64];
  __shared__ __align__(16) bf16 P_lds[4][2][16][40];
  const int orig = blockIdx.x;                 // 640 = 8 XCD * 80
  const int bid = (orig & 7) * 80 + (orig >> 3);
  const bf16* Vt; int qoff, koff, colOff; bool bias;
  int b, h, qblk;
  if (bid < 256) {
    Vt = Vtp; qoff = 0; koff = 256; colOff = 0; bias = false;
    b = bid >> 5; h = (bid >> 3) & 3; qblk = bid & 7;
  } else if (bid < 512) {
    int i = bid - 256;
    Vt = Vts; qoff = 768; koff = 1024; colOff = 256; bias = true;
    b = i >> 5; h = (i >> 3) & 3; qblk = i & 7;
  } else {
    int i = bid - 512;
    Vt = Vtt; qoff = 1536; koff = 1664; colOff = 512; bias = false;
    b = i >> 4; h = (i >> 3) & 1; qblk = i & 7;
  }
  const int E3 = 1920;
  const int qcol = h * 64;
  const int tid = threadIdx.x;
  const int w = tid >> 6, l = tid & 63;
  const int g = l >> 4, c = l & 15;
  const int q0 = qblk * 64 + w * 16;
  const int tok0 = b * 512;
  const float scale = 0.125f;

  const bf16* qrow = qkv + (size_t)(tok0 + q0 + c) * E3 + qoff + qcol;
  bf16x8 qf0 = *(const bf16x8*)(qrow + g * 8);
  bf16x8 qf1 = *(const bf16x8*)(qrow + 32 + g * 8);
  const bf16* Kb = qkv + (size_t)tok0 * E3 + koff + qcol;
  const bf16* pmq = pmb + (size_t)(tok0 + q0 + c) * 512;   // q = c (swapped layout)

  const int ciA = tid, ciB = 256 + tid;
  const int rA = ciA >> 3, cA = ciA & 7;
  const int rB = ciB >> 3, cB = ciB & 7;
  const bf16* kSrcA = Kb + (size_t)rA * E3 + ((cA ^ (rA & 7)) << 3);
  const bf16* kSrcB = Kb + (size_t)rB * E3 + ((cB ^ (rB & 7)) << 3);
  const bf16* vSrcA = Vt + (size_t)(qcol + rA) * 4096 + tok0 + ((cA ^ (rA & 7)) << 3);
  const bf16* vSrcB = Vt + (size_t)(qcol + rB) * 4096 + tok0 + ((cB ^ (rB & 7)) << 3);
  bf16* kDstA = &Ks[(size_t)w * 512];
  bf16* kDstB = &Ks[2048 + (size_t)w * 512];
  bf16* vDstA = &Vs[(size_t)w * 512];
  bf16* vDstB = &Vs[2048 + (size_t)w * 512];

  float sm = 0.f;
  f32x4 oT[4] = {};
  const int cx = c & 7;

  for (int it = 0; it < 8; ++it) {
    const int kt = it * 64;
    if (it) __syncthreads();
    glds16(kSrcA, kDstA); glds16(kSrcB, kDstB);
    glds16(vSrcA, vDstA); glds16(vSrcB, vDstB);
    kSrcA += (size_t)64 * E3; kSrcB += (size_t)64 * E3;
    vSrcA += 64; vSrcB += 64;
    __syncthreads();

    f32x4 s[4] = {};
    __builtin_amdgcn_s_setprio(1);
#pragma unroll
    for (int j = 0; j < 4; ++j) {
      const int row = 16 * j + c;
      bf16x8 k0 = *(const bf16x8*)&Ks[row * 64 + ((g ^ cx) << 3)];
      bf16x8 k1 = *(const bf16x8*)&Ks[row * 64 + (((4 + g) ^ cx) << 3)];
      s[j] = MFMA(k0, qf0, s[j]);
      s[j] = MFMA(k1, qf1, s[j]);
    }
    __builtin_amdgcn_s_setprio(0);
#pragma unroll
    for (int j = 0; j < 4; ++j) {
      bf16x4 e;
      float a0 = s[j][0] * scale, a1 = s[j][1] * scale;
      float a2 = s[j][2] * scale, a3 = s[j][3] * scale;
      if (bias) {
        bf16x4 bb = *(const bf16x4*)(pmq + kt + 16 * j + 4 * g);
        a0 += (float)bb[0]; a1 += (float)bb[1];
        a2 += (float)bb[2]; a3 += (float)bb[3];
      }
      float x0 = __expf(a0), x1 = __expf(a1);
      float x2 = __expf(a2), x3 = __expf(a3);
      sm += (x0 + x1) + (x2 + x3);
      e[0] = (bf16)x0; e[1] = (bf16)x1; e[2] = (bf16)x2; e[3] = (bf16)x3;
      *(bf16x4*)&P_lds[w][j >> 1][c][(j & 1) * 16 + 4 * g] = e;
    }
    asm volatile("s_waitcnt lgkmcnt(0)" ::: "memory");
    __builtin_amdgcn_s_setprio(1);
#pragma unroll
    for (int hf = 0; hf < 2; ++hf) {
      bf16x8 pf = *(const bf16x8*)&P_lds[w][hf][c][g * 8];
#pragma unroll
      for (int dt = 0; dt < 4; ++dt) {
        const int vrow = dt * 16 + c;
        bf16x8 vf = *(const bf16x8*)&Vs[vrow * 64 + (((hf * 4 + g) ^ cx) << 3)];
        oT[dt] = MFMA(vf, pf, oT[dt]);
      }
    }
    __builtin_amdgcn_s_setprio(0);
  }

  sm += __shfl_xor(sm, 16);
  sm += __shfl_xor(sm, 32);
  const float inv = 1.0f / sm;
#pragma unroll
  for (int dt = 0; dt < 4; ++dt) {
    bf16x4 o4;
#pragma unroll
    for (int r = 0; r < 4; ++r) o4[r] = (bf16)(oT[dt][r] * inv);
    *(bf16x4*)(out + (size_t)(tok0 + q0 + c) * 640 + colOff + qcol + dt * 16 + 4 * g) = o4;
  }
}

// LayerNorm over D=640, one wave per row, bf16 out.
__global__ __launch_bounds__(256) void ln_kernel(
    const float* __restrict__ x, const float* __restrict__ sca,
    const float* __restrict__ bia, bf16* __restrict__ out)
{
  const int w = threadIdx.x >> 6, l = threadIdx.x & 63;
  const int row = blockIdx.x * 4 + w;
  const float* xr = x + (size_t)row * 640;
  float v[10], sum = 0.f, sq = 0.f;
#pragma unroll
  for (int i = 0; i < 10; ++i) {
    v[i] = xr[l + 64 * i];
    sum += v[i]; sq += v[i] * v[i];
  }
#pragma unroll
  for (int m = 1; m <= 32; m <<= 1) {
    sum += __shfl_xor(sum, m);
    sq  += __shfl_xor(sq, m);
  }
  const float mean = sum * (1.f / 640.f);
  const float var  = sq * (1.f / 640.f) - mean * mean;
  const float rstd = rsqrtf(var + 1e-5f);
  bf16* orow = out + (size_t)row * 640;
#pragma unroll
  for (int i = 0; i < 10; ++i) {
    const int c = l + 64 * i;
    orow[c] = (bf16)((v[i] - mean) * rstd * sca[c] + bia[c]);
  }
}

__global__ void cvt_bf16_k(const float* __restrict__ src, bf16* __restrict__ dst,
                           int perL, int dstStride, int dstOff, int total, float scl)
{
  int i = blockIdx.x * 256 + threadIdx.x;
  if (i >= total) return;
  int l = i / perL, j = i - l * perL;
  dst[(size_t)l * dstStride + dstOff + j] = (bf16)(scl * src[i]);
}

__global__ void cvt_f32_k(const float* __restrict__ src, float* __restrict__ dst,
                          int perL, int dstStride, int dstOff, int total)
{
  int i = blockIdx.x * 256 + threadIdx.x;
  if (i >= total) return;
  int l = i / perL, j = i - l * perL;
  dst[(size_t)l * dstStride + dstOff + j] = src[i];
}

__global__ void tcvt_k(const float* __restrict__ src, bf16* __restrict__ dst,
                       int R, int C)
{
  __shared__ float t[32][33];
  const int lz = blockIdx.z;
  src += (size_t)lz * R * C;
  dst += (size_t)lz * R * C;
  const int c0 = blockIdx.x * 32, r0 = blockIdx.y * 32;
  const int tx = threadIdx.x & 31, ty = threadIdx.x >> 5;
#pragma unroll
  for (int i = ty; i < 32; i += 8)
    t[i][tx] = src[(size_t)(r0 + i) * C + c0 + tx];
  __syncthreads();
#pragma unroll
  for (int i = ty; i < 32; i += 8)
    dst[(size_t)(c0 + i) * R + r0 + tx] = (bf16)t[tx][i];
}

__global__ void biasmix_k(const float* __restrict__ b2, int b2S,
                          const float* __restrict__ W2, long long w2S, int ldw,
                          const float* __restrict__ b1, int b1S,
                          float* __restrict__ dst, int dstS, int dstOff,
                          int M, int K)
{
  const int lz = blockIdx.y;
  const int w = threadIdx.x >> 6, lane = threadIdx.x & 63;
  const int m = blockIdx.x * 4 + w;
  if (m >= M) return;
  const float* wr = W2 + (size_t)lz * w2S + (size_t)m * ldw;
  const float* br = b1 + (size_t)lz * b1S;
  float s = 0.f;
  for (int k = lane; k < K; k += 64) s += wr[k] * br[k];
#pragma unroll
  for (int msk = 1; msk <= 32; msk <<= 1) s += __shfl_xor(s, msk);
  if (lane == 0)
    dst[(size_t)lz * dstS + dstOff + m] = s + b2[(size_t)lz * b2S + m];
}

__global__ void copy_f32(const float* __restrict__ src, float* __restrict__ dst, int n)
{
  int i = blockIdx.x * 256 + threadIdx.x;
  if (i < n) dst[i] = src[i];
}

extern "C" void kernel_launch(void* const* d_in, const int* in_sizes, int n_in,
                              void* d_out, int out_size, void* d_ws, size_t ws_size,
                              hipStream_t stream)
{
  (void)in_sizes; (void)n_in; (void)ws_size;
  const float* src    = (const float*)d_in[0];
  const float* pmask  = (const float*)d_in[1];
  const float* n1_s   = (const float*)d_in[3];
  const float* n1_b   = (const float*)d_in[4];
  const float* pin_W  = (const float*)d_in[5];
  const float* pin_b  = (const float*)d_in[6];
  const float* sin_W  = (const float*)d_in[7];
  const float* sin_b  = (const float*)d_in[8];
  const float* tin_W  = (const float*)d_in[9];
  const float* tin_b  = (const float*)d_in[10];
  const float* pqkv_W = (const float*)d_in[11];
  const float* pqkv_b = (const float*)d_in[12];
  const float* pout_W = (const float*)d_in[13];
  const float* pout_b = (const float*)d_in[14];
  const float* sqkv_W = (const float*)d_in[15];
  const float* sqkv_b = (const float*)d_in[16];
  const float* sout_W = (const float*)d_in[17];
  const float* sout_b = (const float*)d_in[18];
  const float* tqkv_W = (const float*)d_in[19];
  const float* tqkv_b = (const float*)d_in[20];
  const float* tout_W = (const float*)d_in[21];
  const float* tout_b = (const float*)d_in[22];
  const float* o_W    = (const float*)d_in[23];
  const float* o_b    = (const float*)d_in[24];
  const float* ff1_W  = (const float*)d_in[25];
  const float* ff1_b  = (const float*)d_in[26];
  const float* ff2_W  = (const float*)d_in[27];
  const float* ff2_b  = (const float*)d_in[28];
  const float* n2_s   = (const float*)d_in[29];
  const float* n2_b   = (const float*)d_in[30];

  char* wsp = (char*)d_ws;
  auto alloc = [&](size_t bytes) {
    char* p = wsp;
    wsp += (bytes + 255) & ~(size_t)255;
    return p;
  };
  bf16*  Wbig   = (bf16*)alloc(6ull * 1920 * 640 * 2);
  float* bbig   = (float*)alloc(6ull * 1920 * 4);
  bf16*  Weff   = (bf16*)alloc(6ull * 640 * 640 * 2);
  float* beff   = (float*)alloc(6ull * 640 * 4);
  float* catb   = (float*)alloc(6ull * 640 * 4);
  bf16*  Wf1    = (bf16*)alloc(6ull * 2048 * 640 * 2);
  bf16*  Wf2    = (bf16*)alloc(6ull * 2048 * 640 * 2);
  bf16*  xn     = (bf16*)alloc(4096ull * 640 * 2);
  bf16*  Vtp    = (bf16*)alloc(256ull * 4096 * 2);
  bf16*  Vts    = (bf16*)alloc(256ull * 4096 * 2);
  bf16*  Vtt    = (bf16*)alloc(128ull * 4096 * 2);
  bf16*  ao     = (bf16*)alloc(4096ull * 640 * 2);
  bf16*  pmb    = (bf16*)alloc(8ull * 512 * 512 * 2);
  char*  region = alloc(4096ull * 1920 * 2 + 4096ull * 2048 * 2);
  bf16*  qkv    = (bf16*)region;
  bf16*  hbuf   = (bf16*)(region + 4096ull * 1920 * 2);
  char* pr = region;
  auto palloc = [&](size_t bytes) {
    char* p = pr;
    pr += (bytes + 255) & ~(size_t)255;
    return p;
  };
  bf16* Wpq  = (bf16*)palloc(6ull * 768 * 256 * 2);
  bf16* Wsq  = (bf16*)palloc(6ull * 768 * 256 * 2);
  bf16* Wtq  = (bf16*)palloc(6ull * 384 * 128 * 2);
  bf16* pinT = (bf16*)palloc(6ull * 640 * 256 * 2);
  bf16* sinT = (bf16*)palloc(6ull * 640 * 256 * 2);
  bf16* tinT = (bf16*)palloc(6ull * 640 * 128 * 2);
  bf16* Wobf = (bf16*)palloc(6ull * 640 * 640 * 2);
  bf16* WpoT = (bf16*)palloc(6ull * 256 * 256 * 2);
  bf16* WsoT = (bf16*)palloc(6ull * 256 * 256 * 2);
  bf16* WtoT = (bf16*)palloc(6ull * 128 * 128 * 2);

  float* x = (float*)d_out;

  auto cvt = [&](const float* s, bf16* d, int perL) {
    int total = 6 * perL;
    cvt_bf16_k<<<(total + 255) / 256, 256, 0, stream>>>(s, d, perL, perL, 0, total, 1.f);
  };
  cvt(pqkv_W, Wpq, 768 * 256);
  cvt(sqkv_W, Wsq, 768 * 256);
  cvt(tqkv_W, Wtq, 384 * 128);
  cvt(o_W,    Wobf, 640 * 640);
  cvt(ff1_W,  Wf1, 2048 * 640);
  cvt(ff2_W,  Wf2, 2048 * 640);
  {
    int total = 8 * 512 * 512;
    cvt_bf16_k<<<(total + 255) / 256, 256, 0, stream>>>(pmask, pmb, total, total, 0, total, 2.f);
  }
  tcvt_k<<<dim3(20, 8, 6), 256, 0, stream>>>(pin_W, pinT, 256, 640);
  tcvt_k<<<dim3(20, 8, 6), 256, 0, stream>>>(sin_W, sinT, 256, 640);
  tcvt_k<<<dim3(20, 4, 6), 256, 0, stream>>>(tin_W, tinT, 128, 640);
  tcvt_k<<<dim3(8, 8, 6), 256, 0, stream>>>(pout_W, WpoT, 256, 256);
  tcvt_k<<<dim3(8, 8, 6), 256, 0, stream>>>(sout_W, WsoT, 256, 256);
  tcvt_k<<<dim3(4, 4, 6), 256, 0, stream>>>(tout_W, WtoT, 128, 128);
  biasmix_k<<<dim3(192, 6), 256, 0, stream>>>(pqkv_b, 768, pqkv_W, 768 * 256, 256,
                                              pin_b, 256, bbig, 1920, 0, 768, 256);
  biasmix_k<<<dim3(192, 6), 256, 0, stream>>>(sqkv_b, 768, sqkv_W, 768 * 256, 256,
                                              sin_b, 256, bbig, 1920, 768, 768, 256);
  biasmix_k<<<dim3(96, 6), 256, 0, stream>>>(tqkv_b, 384, tqkv_W, 384 * 128, 128,
                                             tin_b, 128, bbig, 1920, 1536, 384, 128);
  cvt_f32_k<<<dim3(6), 256, 0, stream>>>(pout_b, catb, 256, 640, 0,   6 * 256);
  cvt_f32_k<<<dim3(6), 256, 0, stream>>>(sout_b, catb, 256, 640, 256, 6 * 256);
  cvt_f32_k<<<dim3(3), 256, 0, stream>>>(tout_b, catb, 128, 640, 512, 6 * 128);
  biasmix_k<<<dim3(160, 6), 256, 0, stream>>>(o_b, 640, o_W, 640 * 640, 640,
                                              catb, 640, beff, 640, 0, 640, 640);
  gemm_bt<0><<<dim3(5, 6, 6), 256, 0, stream>>>(Wpq, 256, 768 * 256, pinT, 640 * 256,
      nullptr, Wbig, 640, 1920 * 640, 256);
  gemm_bt<0><<<dim3(5, 6, 6), 256, 0, stream>>>(Wsq, 256, 768 * 256, sinT, 640 * 256,
      nullptr, Wbig + 768 * 640, 640, 1920 * 640, 256);
  gemm_bt<0><<<dim3(5, 3, 6), 256, 0, stream>>>(Wtq, 128, 384 * 128, tinT, 640 * 128,
      nullptr, Wbig + 1536 * 640, 640, 1920 * 640, 128);
  gemm_bt<0><<<dim3(2, 5, 6), 256, 0, stream>>>(Wobf, 640, 640 * 640, WpoT, 256 * 256,
      nullptr, Weff, 640, 640 * 640, 256);
  gemm_bt<0><<<dim3(2, 5, 6), 256, 0, stream>>>(Wobf + 256, 640, 640 * 640, WsoT, 256 * 256,
      nullptr, Weff + 256, 640, 640 * 640, 256);
  gemm_bt<0><<<dim3(1, 5, 6), 256, 0, stream>>>(Wobf + 512, 640, 640 * 640, WtoT, 128 * 128,
      nullptr, Weff + 512, 640, 640 * 640, 128);

  copy_f32<<<(out_size + 255) / 256, 256, 0, stream>>>(src, x, out_size);

  for (int l = 0; l < 6; ++l) {
    ln_kernel<<<1024, 256, 0, stream>>>(x, n1_s + l * 640, n1_b + l * 640, xn);
    gemm_h64<3, 1><<<dim3(15, 64), 256, 0, stream>>>(xn, 640,
        Wbig + (size_t)l * 1920 * 640, 640, bbig + l * 1920,
        qkv, 1920, 640, Vtp, Vts, Vtt);
    attn_full<<<640, 256, 0, stream>>>(qkv, Vtp, Vts, Vtt, pmb, ao);
    gemm_h64<2, 2><<<dim3(5, 64, 2), 256, 0, stream>>>(ao, 640,
        Weff + (size_t)l * 640 * 640, 640, beff + l * 640,
        x, 640, 640, nullptr, nullptr, nullptr);
    ln_kernel<<<1024, 256, 0, stream>>>(x, n2_s + l * 640, n2_b + l * 640, xn);
    gemm_h64<1, 1><<<dim3(16, 64), 256, 0, stream>>>(xn, 640,
        Wf1 + (size_t)l * 2048 * 640, 640, ff1_b + l * 2048,
        hbuf, 2048, 640, nullptr, nullptr, nullptr);
    gemm_h64<2, 2><<<dim3(5, 64, 2), 256, 0, stream>>>(hbuf, 2048,
        Wf2 + (size_t)l * 2048 * 640, 2048, ff2_b + l * 640,
        x, 640, 2048, nullptr, nullptr, nullptr);
  }
}